// Round 14
// baseline (810.912 us; speedup 1.0000x reference)
//
#include <hip/hip_runtime.h>
#include <math.h>

#define NN   16384
#define EE   262144

typedef __attribute__((ext_vector_type(8))) short  short8v;   // 8 bf16 = 4 VGPR
typedef __attribute__((ext_vector_type(4))) float  f32x4;

__device__ inline unsigned short f2bf(float f) {
    union { float f; unsigned u; } v; v.f = f;
    unsigned r = v.u + 0x7fff + ((v.u >> 16) & 1);   // RNE
    return (unsigned short)(r >> 16);
}
__device__ inline float bf2f(unsigned short b) {
    unsigned u = ((unsigned)b) << 16;
    union { unsigned u; float f; } v; v.u = u; return v.f;
}
__device__ inline float sigm_f(float x) { return 1.f / (1.f + __expf(-x)); }
__device__ inline float tanh_f(float x) {
    x = fminf(15.f, fmaxf(-15.f, x));
    float e = __expf(2.f * x);
    return (e - 1.f) / (e + 1.f);
}
// quarter-split gate-col permutation:
// n'' = Q*256 + wv*32 + tile*16 + tc,  tile in {0,1}, tc in [0,16)
// gate g = tile*2 + (tc>>3), hidden j = Q*64 + wv*8 + (tc&7), orig = g*256 + j
__device__ inline int gate_orig2(int np) {
    int Q = np >> 8, wv = (np >> 5) & 7, tile = (np >> 4) & 1, tc = np & 15;
    int g = tile * 2 + (tc >> 3);
    int j = Q * 64 + wv * 8 + (tc & 7);
    return g * 256 + j;
}

// direct global->LDS async copy, 16 B/lane; lds dest = wave-uniform base + lane*16
__device__ __forceinline__ void gload16(const unsigned short* g, unsigned short* l) {
    __builtin_amdgcn_global_load_lds(
        (const __attribute__((address_space(1))) void*)g,
        (__attribute__((address_space(3))) void*)l,
        16, 0, 0);
}

// ---------------- init (zero hx tags / deg / fill) ----------------
__global__ void k_init(unsigned long long* __restrict__ hx, int* __restrict__ deg,
                       int* __restrict__ fill) {
    int i = blockIdx.x * 256 + threadIdx.x;
    if (i < 65536) hx[i] = 0ull;            // tag=0 matches no wanted tag (>=1)
    if (i < NN) { deg[i] = 0; fill[i] = 0; }
}

// ---------------- embedding gather -> bf16, K padded 300->320 ----------------
__global__ void k_embed_bf(const int* __restrict__ wseq, const float* __restrict__ tab,
                           unsigned short* __restrict__ xeb) {
    int i = blockIdx.x * 256 + threadIdx.x;
    if (i >= NN * 320) return;
    int row = i / 320, k = i - row * 320;
    float f = (k < 300) ? tab[wseq[row] * 300 + k] : 0.f;
    xeb[i] = f2bf(f);
}

// ---------------- weight conversions (gate_orig2 permutation) ----------------
__global__ void k_cvt_wih(const float* __restrict__ wih, unsigned short* __restrict__ wt) {
    int i = blockIdx.x * 256 + threadIdx.x;
    if (i >= 1024 * 320) return;
    int np = i / 320, k = i - np * 320;
    wt[i] = f2bf(k < 300 ? wih[gate_orig2(np) * 300 + k] : 0.f);
}
__global__ void k_cvt_whh(const float* __restrict__ whh, unsigned short* __restrict__ wp) {
    int i = blockIdx.x * 256 + threadIdx.x;
    if (i >= 1024 * 256) return;
    int np = i >> 8, k = i & 255;
    wp[i] = f2bf(whh[gate_orig2(np) * 256 + k]);
}
__global__ void k_permb(const float* __restrict__ b, float* __restrict__ pb) {
    int i = blockIdx.x * 256 + threadIdx.x;
    if (i < 1024) pb[i] = b[gate_orig2(i)];
}
__global__ void k_cvt_wcat(const float* __restrict__ Wl, const float* __restrict__ Wr,
                           unsigned short* __restrict__ wc) {
    int i = blockIdx.x * 256 + threadIdx.x;
    if (i >= 512 * 1024) return;
    int n = i >> 10, k = i & 1023;
    float f = (k < 512) ? Wl[k * 512 + n] : Wr[(k - 512) * 512 + n];
    wc[i] = f2bf(f);
}

// ---------------- bf16 MFMA GEMM: C[M][N] = A[M][Ka] * Bt[N][Ka]^T + bias ----------------
__global__ __launch_bounds__(256)
void k_mgemm(const unsigned short* __restrict__ A, const unsigned short* __restrict__ Bt,
             const float* __restrict__ bias, float* __restrict__ C, int N, int Ka)
{
    __shared__ __align__(16) unsigned short As[128 * 32];
    __shared__ __align__(16) unsigned short Bs[128 * 32];
    const int tid = threadIdx.x;
    const int m0 = blockIdx.x << 7, n0 = blockIdx.y << 7;
    const int w = tid >> 6, lane = tid & 63;
    const int wr = w >> 1, wc = w & 1;
    const int lr = lane & 15, lhi = lane >> 4;
    const int rA  = w * 16 + (lane >> 2);
    const int kcA = (lane & 3) * 8;

    const unsigned short* gA0 = A  + (size_t)(m0 + rA) * Ka + kcA;
    const unsigned short* gA1 = gA0 + (size_t)64 * Ka;
    const unsigned short* gB0 = Bt + (size_t)(n0 + rA) * Ka + kcA;
    const unsigned short* gB1 = gB0 + (size_t)64 * Ka;
    unsigned short* lA0 = As + w * 512;
    unsigned short* lA1 = As + 64 * 32 + w * 512;
    unsigned short* lB0 = Bs + w * 512;
    unsigned short* lB1 = Bs + 64 * 32 + w * 512;

    f32x4 acc[4][4] = {};

    for (int k0 = 0; k0 < Ka; k0 += 32) {
        gload16(gA0 + k0, lA0);
        gload16(gA1 + k0, lA1);
        gload16(gB0 + k0, lB0);
        gload16(gB1 + k0, lB1);
        asm volatile("s_waitcnt vmcnt(0)" ::: "memory");
        __syncthreads();
        short8v af[4], bf[4];
        #pragma unroll
        for (int i = 0; i < 4; ++i)
            af[i] = *(const short8v*)&As[(wr * 64 + i * 16 + lr) * 32 + lhi * 8];
        #pragma unroll
        for (int j = 0; j < 4; ++j)
            bf[j] = *(const short8v*)&Bs[(wc * 64 + j * 16 + lr) * 32 + lhi * 8];
        #pragma unroll
        for (int i = 0; i < 4; ++i)
            #pragma unroll
            for (int j = 0; j < 4; ++j)
                acc[i][j] = __builtin_amdgcn_mfma_f32_16x16x32_bf16(af[i], bf[j], acc[i][j], 0, 0, 0);
        __syncthreads();
    }
    #pragma unroll
    for (int i = 0; i < 4; ++i) {
        int row = m0 + wr * 64 + i * 16 + lhi * 4;
        #pragma unroll
        for (int j = 0; j < 4; ++j) {
            int col = n0 + wc * 64 + j * 16 + lr;
            float bv = bias[col];
            #pragma unroll
            for (int r = 0; r < 4; ++r)
                C[(row + r) * N + col] = acc[i][j][r] + bv;
        }
    }
}

// ---------------- LSTM recurrence: quarter-split + 2-slice interleave ----------------
// grid = 32 wgs (dir*16 + bp*4 + Q), 512 thr. Each wg owns 32 batch rows as
// 2 slices of 16. Per step: P1 compute s0 -> P2 poll peers' s1 h(t-1)
// (stored 2 phases ago) -> bar -> P3 compute s1 -> P4 poll peers' s0 h(t)
// (stored 1 phase ago) -> bar. Every poll sits >=1 compute phase after the
// matching remote store, hiding the MALL RT under independent work.
// hx: ((dir*4+bp)*4+Q)*2048 + (slice*2+parity)*512 + tid  (512 KB total).
__global__ __launch_bounds__(512, 2)
void k_lstm(const float* __restrict__ xs_f, const float* __restrict__ xs_b,
            const unsigned short* __restrict__ whhp_f, const unsigned short* __restrict__ whhp_b,
            unsigned short* __restrict__ xout, unsigned long long* __restrict__ hx)
{
    const int tid  = threadIdx.x;
    const int wv   = tid >> 6, lane = tid & 63;
    const int lr16 = lane & 15, lh = lane >> 4;
    const int b3   = (lane >> 3) & 1, lr3 = lane & 7;
    const int wgid = blockIdx.x;            // dir*16 + bp*4 + Q
    const int dir  = wgid >> 4;
    const int bp   = (wgid >> 2) & 3;
    const int Q    = wgid & 3;
    const int b0s0 = bp * 32, b0s1 = bp * 32 + 16;
    const float* xs = dir ? xs_b : xs_f;
    const unsigned short* whhp = dir ? whhp_b : whhp_f;

    // B-frag preload: 2 tiles x 8 ks = 64 VGPRs (compiler may rematerialize;
    // that is the r10-measured steady state)
    const int ncol0 = Q * 256 + wv * 32 + lr16;     // tile0 col; tile1 = +16
    short8v wf[2][8];
    #pragma unroll
    for (int tt = 0; tt < 2; ++tt)
        #pragma unroll
        for (int ks = 0; ks < 8; ++ks)
            wf[tt][ks] = *(const short8v*)(whhp
                + (size_t)(ncol0 + tt * 16) * 256 + ks * 32 + lh * 8);

    __shared__ unsigned short At[2][2][16 * 256];   // [slice][parity][row][j], swizzled

    const int grpQ = (dir * 4 + bp) * 4;            // group of 4 quarter-wgs
    unsigned long long* hx_own = hx + (size_t)(grpQ + Q) * 2048;
    const unsigned long long* hx_p1 = hx + (size_t)(grpQ + (Q ^ 1)) * 2048;
    const unsigned long long* hx_p2 = hx + (size_t)(grpQ + (Q ^ 2)) * 2048;
    const unsigned long long* hx_p3 = hx + (size_t)(grpQ + (Q ^ 3)) * 2048;

    const int jmine = Q * 64 + wv * 8 + lr3;        // my hidden index
    const int rowb  = 4 * lh;
    const int myr0  = rowb + 2 * b3;                // my 2 rows within slice
    const int up_jl = (tid >> 6) * 8 + (tid & 7);
    const int up_r0 = 2 * ((tid >> 3) & 7);
    const int j1 = (Q ^ 1) * 64 + up_jl;
    const int j2 = (Q ^ 2) * 64 + up_jl;
    const int j3 = (Q ^ 3) * 64 + up_jl;

    float c0a = 0.f, c1a = 0.f;                     // slice0 cell states
    float c0b = 0.f, c1b = 0.f;                     // slice1 cell states
    float xva0[4], xva1[4], xvb0[4], xvb1[4];
    {
        const int l0 = dir ? 127 : 0;
        #pragma unroll
        for (int r = 0; r < 4; ++r) {
            const float* xpa = xs + ((size_t)(b0s0 + rowb + r) * 128 + l0) * 1024;
            const float* xpb = xs + ((size_t)(b0s1 + rowb + r) * 128 + l0) * 1024;
            xva0[r] = xpa[ncol0]; xva1[r] = xpa[ncol0 + 16];
            xvb0[r] = xpb[ncol0]; xvb1[r] = xpb[ncol0 + 16];
        }
    }

    for (int t = 0; t < 128; ++t) {
        const int l  = dir ? (127 - t) : t;
        const int l2 = dir ? (126 - t) : (t + 1);
        const int p  = t & 1, q = p ^ 1;
        const unsigned tg  = (unsigned)t;           // tag of h(t-1)
        const unsigned tg1 = (unsigned)(t + 1);     // tag of h(t)

        // ---------- P1: slice 0 compute ----------
        {
            f32x4 acc0 = {}, acc1 = {};
            if (t > 0) {
                const char* Ab = (const char*)&At[0][q][0];
                #pragma unroll
                for (int ks = 0; ks < 8; ++ks) {
                    int off = (lr16 * 512 + ks * 64 + lh * 16) ^ ((lr16 & 7) << 4);
                    short8v a = *(const short8v*)(Ab + off);
                    acc0 = __builtin_amdgcn_mfma_f32_16x16x32_bf16(a, wf[0][ks], acc0, 0, 0, 0);
                    acc1 = __builtin_amdgcn_mfma_f32_16x16x32_bf16(a, wf[1][ks], acc1, 0, 0, 0);
                }
            }
            #pragma unroll
            for (int r = 0; r < 4; ++r) { acc0[r] += xva0[r]; acc1[r] += xva1[r]; }
            float z0 = b3 ? acc0[0] : acc0[2];
            float z1 = b3 ? acc0[1] : acc0[3];
            float z2 = b3 ? acc1[0] : acc1[2];
            float z3 = b3 ? acc1[1] : acc1[3];
            float y0 = __shfl_xor(z0, 8);
            float y1 = __shfl_xor(z1, 8);
            float y2 = __shfl_xor(z2, 8);
            float y3 = __shfl_xor(z3, 8);
            float iv0 = b3 ? y0 : acc0[0], iv1 = b3 ? y1 : acc0[1];
            float fv0 = b3 ? acc0[2] : y0, fv1 = b3 ? acc0[3] : y1;
            float gv0 = b3 ? y2 : acc1[0], gv1 = b3 ? y3 : acc1[1];
            float ov0 = b3 ? acc1[2] : y2, ov1 = b3 ? acc1[3] : y3;
            iv0 = sigm_f(iv0); fv0 = sigm_f(fv0); gv0 = tanh_f(gv0); ov0 = sigm_f(ov0);
            c0a = fv0 * c0a + iv0 * gv0;
            float h0 = ov0 * tanh_f(c0a);
            iv1 = sigm_f(iv1); fv1 = sigm_f(fv1); gv1 = tanh_f(gv1); ov1 = sigm_f(ov1);
            c1a = fv1 * c1a + iv1 * gv1;
            float h1 = ov1 * tanh_f(c1a);
            unsigned short hb0 = f2bf(h0), hb1 = f2bf(h1);
            xout[((size_t)(b0s0 + myr0)     * 128 + l) * 512 + dir * 256 + jmine] = hb0;
            xout[((size_t)(b0s0 + myr0 + 1) * 128 + l) * 512 + dir * 256 + jmine] = hb1;
            if (t < 127) {
                char* Aw = (char*)&At[0][p][0];
                int r0_ = myr0, r1_ = myr0 + 1;
                *(unsigned short*)(Aw + ((r0_ * 512 + 2 * jmine) ^ ((r0_ & 7) << 4))) = hb0;
                *(unsigned short*)(Aw + ((r1_ * 512 + 2 * jmine) ^ ((r1_ & 7) << 4))) = hb1;
                unsigned long long w = ((unsigned long long)tg1 << 32)
                                     | ((unsigned)hb0 | ((unsigned)hb1 << 16));
                __hip_atomic_store(hx_own + (0 * 2 + p) * 512 + tid, w,
                                   __ATOMIC_RELAXED, __HIP_MEMORY_SCOPE_AGENT);
                #pragma unroll
                for (int r = 0; r < 4; ++r) {
                    const float* xp = xs + ((size_t)(b0s0 + rowb + r) * 128 + l2) * 1024;
                    xva0[r] = xp[ncol0]; xva1[r] = xp[ncol0 + 16];
                }
            }
        }
        // ---------- P2: poll peers' slice1 h(t-1) (stored 2 phases ago) ----------
        if (t > 0) {
            const int so = (1 * 2 + q) * 512 + tid;
            unsigned long long u1 = __hip_atomic_load(hx_p1 + so, __ATOMIC_RELAXED, __HIP_MEMORY_SCOPE_AGENT);
            unsigned long long u2 = __hip_atomic_load(hx_p2 + so, __ATOMIC_RELAXED, __HIP_MEMORY_SCOPE_AGENT);
            unsigned long long u3 = __hip_atomic_load(hx_p3 + so, __ATOMIC_RELAXED, __HIP_MEMORY_SCOPE_AGENT);
            while ((unsigned)(u1 >> 32) != tg)
                u1 = __hip_atomic_load(hx_p1 + so, __ATOMIC_RELAXED, __HIP_MEMORY_SCOPE_AGENT);
            while ((unsigned)(u2 >> 32) != tg)
                u2 = __hip_atomic_load(hx_p2 + so, __ATOMIC_RELAXED, __HIP_MEMORY_SCOPE_AGENT);
            while ((unsigned)(u3 >> 32) != tg)
                u3 = __hip_atomic_load(hx_p3 + so, __ATOMIC_RELAXED, __HIP_MEMORY_SCOPE_AGENT);
            char* Aw = (char*)&At[1][q][0];
            int ra = up_r0, rb = up_r0 + 1;
            *(unsigned short*)(Aw + ((ra * 512 + 2 * j1) ^ ((ra & 7) << 4))) =
                (unsigned short)(u1 & 0xffff);
            *(unsigned short*)(Aw + ((rb * 512 + 2 * j1) ^ ((rb & 7) << 4))) =
                (unsigned short)((u1 >> 16) & 0xffff);
            *(unsigned short*)(Aw + ((ra * 512 + 2 * j2) ^ ((ra & 7) << 4))) =
                (unsigned short)(u2 & 0xffff);
            *(unsigned short*)(Aw + ((rb * 512 + 2 * j2) ^ ((rb & 7) << 4))) =
                (unsigned short)((u2 >> 16) & 0xffff);
            *(unsigned short*)(Aw + ((ra * 512 + 2 * j3) ^ ((ra & 7) << 4))) =
                (unsigned short)(u3 & 0xffff);
            *(unsigned short*)(Aw + ((rb * 512 + 2 * j3) ^ ((rb & 7) << 4))) =
                (unsigned short)((u3 >> 16) & 0xffff);
        }
        __syncthreads();                            // At[1][q] complete
        // ---------- P3: slice 1 compute ----------
        {
            f32x4 acc0 = {}, acc1 = {};
            if (t > 0) {
                const char* Ab = (const char*)&At[1][q][0];
                #pragma unroll
                for (int ks = 0; ks < 8; ++ks) {
                    int off = (lr16 * 512 + ks * 64 + lh * 16) ^ ((lr16 & 7) << 4);
                    short8v a = *(const short8v*)(Ab + off);
                    acc0 = __builtin_amdgcn_mfma_f32_16x16x32_bf16(a, wf[0][ks], acc0, 0, 0, 0);
                    acc1 = __builtin_amdgcn_mfma_f32_16x16x32_bf16(a, wf[1][ks], acc1, 0, 0, 0);
                }
            }
            #pragma unroll
            for (int r = 0; r < 4; ++r) { acc0[r] += xvb0[r]; acc1[r] += xvb1[r]; }
            float z0 = b3 ? acc0[0] : acc0[2];
            float z1 = b3 ? acc0[1] : acc0[3];
            float z2 = b3 ? acc1[0] : acc1[2];
            float z3 = b3 ? acc1[1] : acc1[3];
            float y0 = __shfl_xor(z0, 8);
            float y1 = __shfl_xor(z1, 8);
            float y2 = __shfl_xor(z2, 8);
            float y3 = __shfl_xor(z3, 8);
            float iv0 = b3 ? y0 : acc0[0], iv1 = b3 ? y1 : acc0[1];
            float fv0 = b3 ? acc0[2] : y0, fv1 = b3 ? acc0[3] : y1;
            float gv0 = b3 ? y2 : acc1[0], gv1 = b3 ? y3 : acc1[1];
            float ov0 = b3 ? acc1[2] : y2, ov1 = b3 ? acc1[3] : y3;
            iv0 = sigm_f(iv0); fv0 = sigm_f(fv0); gv0 = tanh_f(gv0); ov0 = sigm_f(ov0);
            c0b = fv0 * c0b + iv0 * gv0;
            float h0 = ov0 * tanh_f(c0b);
            iv1 = sigm_f(iv1); fv1 = sigm_f(fv1); gv1 = tanh_f(gv1); ov1 = sigm_f(ov1);
            c1b = fv1 * c1b + iv1 * gv1;
            float h1 = ov1 * tanh_f(c1b);
            unsigned short hb0 = f2bf(h0), hb1 = f2bf(h1);
            xout[((size_t)(b0s1 + myr0)     * 128 + l) * 512 + dir * 256 + jmine] = hb0;
            xout[((size_t)(b0s1 + myr0 + 1) * 128 + l) * 512 + dir * 256 + jmine] = hb1;
            if (t < 127) {
                char* Aw = (char*)&At[1][p][0];
                int r0_ = myr0, r1_ = myr0 + 1;
                *(unsigned short*)(Aw + ((r0_ * 512 + 2 * jmine) ^ ((r0_ & 7) << 4))) = hb0;
                *(unsigned short*)(Aw + ((r1_ * 512 + 2 * jmine) ^ ((r1_ & 7) << 4))) = hb1;
                unsigned long long w = ((unsigned long long)tg1 << 32)
                                     | ((unsigned)hb0 | ((unsigned)hb1 << 16));
                __hip_atomic_store(hx_own + (1 * 2 + p) * 512 + tid, w,
                                   __ATOMIC_RELAXED, __HIP_MEMORY_SCOPE_AGENT);
                #pragma unroll
                for (int r = 0; r < 4; ++r) {
                    const float* xp = xs + ((size_t)(b0s1 + rowb + r) * 128 + l2) * 1024;
                    xvb0[r] = xp[ncol0]; xvb1[r] = xp[ncol0 + 16];
                }
            }
        }
        // ---------- P4: poll peers' slice0 h(t) (stored 1 phase ago in P1) ----------
        if (t < 127) {
            const int so = (0 * 2 + p) * 512 + tid;
            unsigned long long u1 = __hip_atomic_load(hx_p1 + so, __ATOMIC_RELAXED, __HIP_MEMORY_SCOPE_AGENT);
            unsigned long long u2 = __hip_atomic_load(hx_p2 + so, __ATOMIC_RELAXED, __HIP_MEMORY_SCOPE_AGENT);
            unsigned long long u3 = __hip_atomic_load(hx_p3 + so, __ATOMIC_RELAXED, __HIP_MEMORY_SCOPE_AGENT);
            while ((unsigned)(u1 >> 32) != tg1)
                u1 = __hip_atomic_load(hx_p1 + so, __ATOMIC_RELAXED, __HIP_MEMORY_SCOPE_AGENT);
            while ((unsigned)(u2 >> 32) != tg1)
                u2 = __hip_atomic_load(hx_p2 + so, __ATOMIC_RELAXED, __HIP_MEMORY_SCOPE_AGENT);
            while ((unsigned)(u3 >> 32) != tg1)
                u3 = __hip_atomic_load(hx_p3 + so, __ATOMIC_RELAXED, __HIP_MEMORY_SCOPE_AGENT);
            char* Aw = (char*)&At[0][p][0];
            int ra = up_r0, rb = up_r0 + 1;
            *(unsigned short*)(Aw + ((ra * 512 + 2 * j1) ^ ((ra & 7) << 4))) =
                (unsigned short)(u1 & 0xffff);
            *(unsigned short*)(Aw + ((rb * 512 + 2 * j1) ^ ((rb & 7) << 4))) =
                (unsigned short)((u1 >> 16) & 0xffff);
            *(unsigned short*)(Aw + ((ra * 512 + 2 * j2) ^ ((ra & 7) << 4))) =
                (unsigned short)(u2 & 0xffff);
            *(unsigned short*)(Aw + ((rb * 512 + 2 * j2) ^ ((rb & 7) << 4))) =
                (unsigned short)((u2 >> 16) & 0xffff);
            *(unsigned short*)(Aw + ((ra * 512 + 2 * j3) ^ ((ra & 7) << 4))) =
                (unsigned short)(u3 & 0xffff);
            *(unsigned short*)(Aw + ((rb * 512 + 2 * j3) ^ ((rb & 7) << 4))) =
                (unsigned short)((u3 >> 16) & 0xffff);
        }
        __syncthreads();                            // At[0][p] complete
    }
}

// ---------------- CSR build ----------------
__global__ void k_hist(const int* __restrict__ ei, int* __restrict__ deg) {
    int e = blockIdx.x * 256 + threadIdx.x;
    if (e >= EE) return;
    atomicAdd(&deg[ei[EE + e]], 1);
}

__global__ void k_scan(const int* __restrict__ deg, int* __restrict__ indptr) {
    __shared__ int sm[256];
    int tid = threadIdx.x;
    int b0 = tid * 64;
    int s = 0;
    for (int i = 0; i < 64; ++i) s += deg[b0 + i];
    sm[tid] = s;
    __syncthreads();
    for (int off = 1; off < 256; off <<= 1) {
        int v = (tid >= off) ? sm[tid - off] : 0;
        __syncthreads();
        sm[tid] += v;
        __syncthreads();
    }
    int run = sm[tid] - s;   // exclusive prefix
    for (int i = 0; i < 64; ++i) { indptr[b0 + i] = run; run += deg[b0 + i]; }
    if (tid == 255) indptr[NN] = run;
}

__global__ void k_scatter(const int* __restrict__ ei, const int* __restrict__ indptr,
                          int* __restrict__ fill, int* __restrict__ cols) {
    int e = blockIdx.x * 256 + threadIdx.x;
    if (e >= EE) return;
    int d = ei[EE + e];
    int slot = atomicAdd(&fill[d], 1);
    cols[indptr[d] + slot] = ei[e];
}

// ---------------- SAGE gather, graph-local via LDS ----------------
__global__ __launch_bounds__(512)
void k_gather_lds(const unsigned short* __restrict__ x, const int* __restrict__ indptr,
                  const int* __restrict__ cols, unsigned short* __restrict__ catb)
{
    extern __shared__ char gsm[];
    unsigned short* Xs = (unsigned short*)gsm;     // [128][512] bf16 = 128 KB
    const int tid  = threadIdx.x;
    const int g    = blockIdx.x >> 1;
    const int hf   = blockIdx.x & 1;
    const int base = g * 128;
    {   // stage: 131072 B = 512 thr x 16 B x 16 iters, fully coalesced
        const unsigned short* src = x + (size_t)base * 512;
        #pragma unroll
        for (int it = 0; it < 16; ++it) {
            int i = it * 512 + tid;                // 16B-chunk index; 64 chunks/row
            int row = i >> 6, c = (i & 63) * 8;
            *(short8v*)(Xs + row * 512 + c) = *(const short8v*)(src + (size_t)row * 512 + c);
        }
    }
    __syncthreads();
    const int wv = tid >> 6, lane = tid & 63;
    for (int rr = 0; rr < 8; ++rr) {
        int node = base + hf * 64 + rr * 8 + wv;
        int s = indptr[node], e = indptr[node + 1];
        float a[8] = {};
        for (int p = s; p < e; ++p) {
            int lrow = cols[p] - base;             // local row in [0,128)
            short8v v = *(const short8v*)(Xs + lrow * 512 + lane * 8);
            #pragma unroll
            for (int q = 0; q < 8; ++q) a[q] += bf2f((unsigned short)v[q]);
        }
        float sc = 1.f / (float)((e - s) > 1 ? (e - s) : 1);
        unsigned short o[8];
        #pragma unroll
        for (int q = 0; q < 8; ++q) o[q] = f2bf(a[q] * sc);
        unsigned short* cp = catb + (size_t)node * 1024 + lane * 8;
        *(short8v*)cp = *(short8v*)o;
        *(short8v*)(cp + 512) = *(const short8v*)(Xs + (node - base) * 512 + lane * 8);
    }
}

// ---------------- row L2-normalize + relu: fp32 in -> bf16 out ----------------
__global__ __launch_bounds__(256)
void k_norm_relu_bf(const float* __restrict__ y, unsigned short* __restrict__ o)
{
    int gw = (blockIdx.x * 256 + threadIdx.x) >> 6;
    int lane = threadIdx.x & 63;
    if (gw >= NN) return;
    const float* row = y + gw * 512 + lane * 8;
    float4 v0 = *(const float4*)row;
    float4 v1 = *(const float4*)(row + 4);
    float ss = v0.x*v0.x + v0.y*v0.y + v0.z*v0.z + v0.w*v0.w
             + v1.x*v1.x + v1.y*v1.y + v1.z*v1.z + v1.w*v1.w;
    #pragma unroll
    for (int off = 32; off >= 1; off >>= 1) ss += __shfl_xor(ss, off);
    float sc = 1.f / fmaxf(sqrtf(ss), 1e-12f);
    unsigned short ob[8];
    ob[0] = f2bf(fmaxf(v0.x*sc, 0.f)); ob[1] = f2bf(fmaxf(v0.y*sc, 0.f));
    ob[2] = f2bf(fmaxf(v0.z*sc, 0.f)); ob[3] = f2bf(fmaxf(v0.w*sc, 0.f));
    ob[4] = f2bf(fmaxf(v1.x*sc, 0.f)); ob[5] = f2bf(fmaxf(v1.y*sc, 0.f));
    ob[6] = f2bf(fmaxf(v1.z*sc, 0.f)); ob[7] = f2bf(fmaxf(v1.w*sc, 0.f));
    *(short8v*)(o + gw * 512 + lane * 8) = *(short8v*)ob;
}

// ---------------- mean-pool per graph + linear head (bf16 in) ----------------
__global__ __launch_bounds__(256)
void k_pool_bf(const unsigned short* __restrict__ x, const float* __restrict__ Wlin,
               const float* __restrict__ blin, float* __restrict__ out)
{
    int g = blockIdx.x;
    int tid = threadIdx.x;
    const unsigned short* base = x + (size_t)g * 128 * 512;
    float a0 = 0.f, a1 = 0.f;
    for (int r = 0; r < 128; ++r) {
        unsigned v = *(const unsigned*)(base + r * 512 + 2 * tid);
        a0 += bf2f((unsigned short)(v & 0xffff));
        a1 += bf2f((unsigned short)(v >> 16));
    }
    __shared__ float pooled[512];
    pooled[2*tid]     = a0 * (1.f / 128.f);
    pooled[2*tid + 1] = a1 * (1.f / 128.f);
    __syncthreads();
    if (tid < 64) {
        float p0 = 0.f, p1 = 0.f;
        for (int k = tid; k < 512; k += 64) {
            float pv = pooled[k];
            p0 += pv * Wlin[2*k];
            p1 += pv * Wlin[2*k + 1];
        }
        #pragma unroll
        for (int off = 32; off >= 1; off >>= 1) {
            p0 += __shfl_xor(p0, off);
            p1 += __shfl_xor(p1, off);
        }
        if (tid == 0) {
            out[2*g]     = p0 + blin[0];
            out[2*g + 1] = p1 + blin[1];
        }
    }
}

extern "C" void kernel_launch(void* const* d_in, const int* in_sizes, int n_in,
                              void* d_out, int out_size, void* d_ws, size_t ws_size,
                              hipStream_t stream)
{
    (void)in_sizes; (void)n_in; (void)out_size; (void)ws_size;
    const int*   word_seq = (const int*)  d_in[0];
    const int*   ei       = (const int*)  d_in[1];
    const float* tab      = (const float*)d_in[3];
    const float* wih_f    = (const float*)d_in[4];
    const float* whh_f    = (const float*)d_in[5];
    const float* b_f      = (const float*)d_in[6];
    const float* wih_b    = (const float*)d_in[7];
    const float* whh_b    = (const float*)d_in[8];
    const float* b_b      = (const float*)d_in[9];
    const float* Wl1      = (const float*)d_in[10];
    const float* Wr1      = (const float*)d_in[11];
    const float* b1       = (const float*)d_in[12];
    const float* Wl2      = (const float*)d_in[13];
    const float* Wr2      = (const float*)d_in[14];
    const float* b2       = (const float*)d_in[15];
    const float* Wl3      = (const float*)d_in[16];
    const float* Wr3      = (const float*)d_in[17];
    const float* b3       = (const float*)d_in[18];
    const float* Wlin     = (const float*)d_in[19];
    const float* blin     = (const float*)d_in[20];
    float* out = (float*)d_out;

    char* w = (char*)d_ws;
    int*   deg    = (int*)  (w);                     //     65,536
    int*   indptr = (int*)  (w + 65536);             //     66,048
    int*   fill   = (int*)  (w + 131584);            //     65,536
    int*   cols   = (int*)  (w + 197120);            //  1,048,576
    unsigned long long* hx = (unsigned long long*)(w + 1245696);   // 524,288
    unsigned short* whhp_f = (unsigned short*)(w + 1769984);       // 524,288
    unsigned short* whhp_b = (unsigned short*)(w + 2294272);       // 524,288
    float* pb_f   = (float*)(w + 2818560);           //      4,096
    float* pb_b   = (float*)(w + 2822656);           //      4,096
    unsigned short* wt_f = (unsigned short*)(w + 2826752);   // 655,360
    unsigned short* wt_b = (unsigned short*)(w + 3482112);   // 655,360
    unsigned short* wc1  = (unsigned short*)(w + 4137472);   // 1,048,576
    unsigned short* wc2  = (unsigned short*)(w + 5186048);   // 1,048,576
    unsigned short* wc3  = (unsigned short*)(w + 6234624);   // 1,048,576
    unsigned short* xeb  = (unsigned short*)(w + 7283200);   // 10,485,760
    float* xs_f   = (float*)(w + 17768960);          // 67,108,864
    float* xs_b   = (float*)(w + 84877824);          // 67,108,864
    unsigned short* x0b = (unsigned short*)(w + 151986688);  // 16,777,216 (end ~161 MB)
    // post-LSTM reuse of xs regions:
    unsigned short* catb = (unsigned short*)(w + 17768960);  // 32 MB in xs_f
    float* x1     = (float*)(w + 51323392);          // 32 MB in xs_f
    unsigned short* xb_a = (unsigned short*)(w + 84877824);  // 16 MB in xs_b
    unsigned short* xb_b = (unsigned short*)(w + 101655040); // 16 MB in xs_b

    // conversions + embedding (bf16)
    k_embed_bf<<<20480, 256, 0, stream>>>(word_seq, tab, xeb);
    k_cvt_wih<<<1280, 256, 0, stream>>>(wih_f, wt_f);
    k_cvt_wih<<<1280, 256, 0, stream>>>(wih_b, wt_b);
    k_cvt_whh<<<1024, 256, 0, stream>>>(whh_f, whhp_f);
    k_cvt_whh<<<1024, 256, 0, stream>>>(whh_b, whhp_b);
    k_permb<<<4, 256, 0, stream>>>(b_f, pb_f);
    k_permb<<<4, 256, 0, stream>>>(b_b, pb_b);
    k_cvt_wcat<<<2048, 256, 0, stream>>>(Wl1, Wr1, wc1);
    k_cvt_wcat<<<2048, 256, 0, stream>>>(Wl2, Wr2, wc2);
    k_cvt_wcat<<<2048, 256, 0, stream>>>(Wl3, Wr3, wc3);

    // CSR build + hx tag clear
    k_init<<<256, 256, 0, stream>>>(hx, deg, fill);
    k_hist<<<1024, 256, 0, stream>>>(ei, deg);
    k_scan<<<1, 256, 0, stream>>>(deg, indptr);
    k_scatter<<<1024, 256, 0, stream>>>(ei, indptr, fill, cols);

    // LSTM input projections (bf16 MFMA): xs = xeb @ wt^T + pb (permuted cols)
    k_mgemm<<<dim3(128, 8), 256, 0, stream>>>(xeb, wt_f, pb_f, xs_f, 1024, 320);
    k_mgemm<<<dim3(128, 8), 256, 0, stream>>>(xeb, wt_b, pb_b, xs_b, 1024, 320);

    // bidirectional LSTM scan -> x0b = [hf | hb] (bf16)
    k_lstm<<<32, 512, 0, stream>>>(xs_f, xs_b, whhp_f, whhp_b, x0b, hx);

    // SAGE layer 1
    k_gather_lds<<<256, 512, 131072, stream>>>(x0b, indptr, cols, catb);
    k_mgemm<<<dim3(128, 4), 256, 0, stream>>>(catb, wc1, b1, x1, 512, 1024);
    k_norm_relu_bf<<<4096, 256, 0, stream>>>(x1, xb_a);
    // SAGE layer 2
    k_gather_lds<<<256, 512, 131072, stream>>>(xb_a, indptr, cols, catb);
    k_mgemm<<<dim3(128, 4), 256, 0, stream>>>(catb, wc2, b2, x1, 512, 1024);
    k_norm_relu_bf<<<4096, 256, 0, stream>>>(x1, xb_b);
    // SAGE layer 3
    k_gather_lds<<<256, 512, 131072, stream>>>(xb_b, indptr, cols, catb);
    k_mgemm<<<dim3(128, 4), 256, 0, stream>>>(catb, wc3, b3, x1, 512, 1024);
    k_norm_relu_bf<<<4096, 256, 0, stream>>>(x1, xb_a);

    // mean pool per graph + linear head
    k_pool_bf<<<128, 256, 0, stream>>>(xb_a, Wlin, blin, out);
}

// Round 15
// 641.751 us; speedup vs baseline: 1.2636x; 1.2636x over previous
//
#include <hip/hip_runtime.h>
#include <math.h>

#define NN   16384
#define EE   262144

typedef __attribute__((ext_vector_type(8))) short  short8v;   // 8 bf16 = 4 VGPR
typedef __attribute__((ext_vector_type(4))) float  f32x4;

__device__ inline unsigned short f2bf(float f) {
    union { float f; unsigned u; } v; v.f = f;
    unsigned r = v.u + 0x7fff + ((v.u >> 16) & 1);   // RNE
    return (unsigned short)(r >> 16);
}
__device__ inline float bf2f(unsigned short b) {
    unsigned u = ((unsigned)b) << 16;
    union { unsigned u; float f; } v; v.u = u; return v.f;
}
__device__ inline float sigm_f(float x) { return 1.f / (1.f + __expf(-x)); }
__device__ inline float tanh_f(float x) {
    x = fminf(15.f, fmaxf(-15.f, x));
    float e = __expf(2.f * x);
    return (e - 1.f) / (e + 1.f);
}
// quarter-split gate-col permutation:
// n'' = Q*256 + wv*32 + tile*16 + tc,  tile in {0,1}, tc in [0,16)
// gate g = tile*2 + (tc>>3), hidden j = Q*64 + wv*8 + (tc&7), orig = g*256 + j
__device__ inline int gate_orig2(int np) {
    int Q = np >> 8, wv = (np >> 5) & 7, tile = (np >> 4) & 1, tc = np & 15;
    int g = tile * 2 + (tc >> 3);
    int j = Q * 64 + wv * 8 + (tc & 7);
    return g * 256 + j;
}

// ---------------- init (zero hx tags / deg / fill) ----------------
__global__ void k_init(unsigned long long* __restrict__ hx, int* __restrict__ deg,
                       int* __restrict__ fill) {
    int i = blockIdx.x * 256 + threadIdx.x;
    if (i < 65536) hx[i] = 0ull;            // tag=0 matches no wanted tag (>=1)
    if (i < NN) { deg[i] = 0; fill[i] = 0; }
}

// ---------------- embedding gather -> bf16, K padded 300->320 (vectorized 16B/thr) ----------------
__global__ void k_embed_bf(const int* __restrict__ wseq, const float* __restrict__ tab,
                           unsigned short* __restrict__ xeb) {
    int i = blockIdx.x * 256 + threadIdx.x;          // chunk of 8 elems
    if (i >= NN * 40) return;
    int row = i / 40, c8 = i - row * 40;
    int k = c8 * 8;
    unsigned short o[8];
    const float* tp = tab + (size_t)wseq[row] * 300;  // row base: 1200 B (16B aligned)
    if (k + 8 <= 300) {
        float4 v0 = *(const float4*)(tp + k);
        float4 v1 = *(const float4*)(tp + k + 4);
        o[0]=f2bf(v0.x); o[1]=f2bf(v0.y); o[2]=f2bf(v0.z); o[3]=f2bf(v0.w);
        o[4]=f2bf(v1.x); o[5]=f2bf(v1.y); o[6]=f2bf(v1.z); o[7]=f2bf(v1.w);
    } else {
        #pragma unroll
        for (int q = 0; q < 8; ++q) {
            int kk = k + q;
            o[q] = f2bf(kk < 300 ? tp[kk] : 0.f);
        }
    }
    *(short8v*)(xeb + (size_t)row * 320 + k) = *(short8v*)o;
}

// ---------------- weight conversions (gate_orig2 permutation, vectorized) ----------------
__global__ void k_cvt_wih(const float* __restrict__ wih, unsigned short* __restrict__ wt) {
    int i = blockIdx.x * 256 + threadIdx.x;
    if (i >= 1024 * 40) return;
    int np = i / 40, c8 = i - np * 40;
    int k = c8 * 8;
    const float* src = wih + (size_t)gate_orig2(np) * 300;   // 1200 B rows, 16B aligned
    unsigned short o[8];
    if (k + 8 <= 300) {
        float4 v0 = *(const float4*)(src + k);
        float4 v1 = *(const float4*)(src + k + 4);
        o[0]=f2bf(v0.x); o[1]=f2bf(v0.y); o[2]=f2bf(v0.z); o[3]=f2bf(v0.w);
        o[4]=f2bf(v1.x); o[5]=f2bf(v1.y); o[6]=f2bf(v1.z); o[7]=f2bf(v1.w);
    } else {
        #pragma unroll
        for (int q = 0; q < 8; ++q) {
            int kk = k + q;
            o[q] = f2bf(kk < 300 ? src[kk] : 0.f);
        }
    }
    *(short8v*)(wt + (size_t)np * 320 + k) = *(short8v*)o;
}
__global__ void k_cvt_whh(const float* __restrict__ whh, unsigned short* __restrict__ wp) {
    int i = blockIdx.x * 256 + threadIdx.x;
    if (i >= 1024 * 32) return;
    int np = i >> 5, kc = i & 31;
    int k = kc * 8;
    const float* src = whh + (size_t)gate_orig2(np) * 256 + k;  // 1024 B rows
    float4 v0 = *(const float4*)src;
    float4 v1 = *(const float4*)(src + 4);
    unsigned short o[8];
    o[0]=f2bf(v0.x); o[1]=f2bf(v0.y); o[2]=f2bf(v0.z); o[3]=f2bf(v0.w);
    o[4]=f2bf(v1.x); o[5]=f2bf(v1.y); o[6]=f2bf(v1.z); o[7]=f2bf(v1.w);
    *(short8v*)(wp + (size_t)np * 256 + k) = *(short8v*)o;
}
__global__ void k_permb(const float* __restrict__ b, float* __restrict__ pb) {
    int i = blockIdx.x * 256 + threadIdx.x;
    if (i < 1024) pb[i] = b[gate_orig2(i)];
}
__global__ void k_cvt_wcat(const float* __restrict__ Wl, const float* __restrict__ Wr,
                           unsigned short* __restrict__ wc) {
    int i = blockIdx.x * 256 + threadIdx.x;
    if (i >= 512 * 1024) return;
    int n = i >> 10, k = i & 1023;
    float f = (k < 512) ? Wl[k * 512 + n] : Wr[(k - 512) * 512 + n];
    wc[i] = f2bf(f);
}

// ---------------- bf16 MFMA GEMM: C[M][N] = A[M][Ka] * Bt[N][Ka]^T + bias ----------------
__global__ __launch_bounds__(256)
void k_mgemm(const unsigned short* __restrict__ A, const unsigned short* __restrict__ Bt,
             const float* __restrict__ bias, float* __restrict__ C, int N, int Ka)
{
    __shared__ unsigned short As[128 * 32];
    __shared__ unsigned short Bs[128 * 32];
    const int tid = threadIdx.x;
    const int m0 = blockIdx.x << 7, n0 = blockIdx.y << 7;
    const int w = tid >> 6, lane = tid & 63;
    const int wr = w >> 1, wc = w & 1;
    const int lr = lane & 15, lhi = lane >> 4;
    const int r0 = tid >> 2, kc0 = (tid & 3) * 8;

    f32x4 acc[4][4] = {};

    for (int k0 = 0; k0 < Ka; k0 += 32) {
        short8v a0 = *(const short8v*)(A + (m0 + r0) * Ka + k0 + kc0);
        short8v a1 = *(const short8v*)(A + (m0 + 64 + r0) * Ka + k0 + kc0);
        short8v b0 = *(const short8v*)(Bt + (n0 + r0) * Ka + k0 + kc0);
        short8v b1 = *(const short8v*)(Bt + (n0 + 64 + r0) * Ka + k0 + kc0);
        __syncthreads();
        *(short8v*)&As[r0 * 32 + kc0]        = a0;
        *(short8v*)&As[(64 + r0) * 32 + kc0] = a1;
        *(short8v*)&Bs[r0 * 32 + kc0]        = b0;
        *(short8v*)&Bs[(64 + r0) * 32 + kc0] = b1;
        __syncthreads();
        short8v af[4], bf[4];
        #pragma unroll
        for (int i = 0; i < 4; ++i)
            af[i] = *(const short8v*)&As[(wr * 64 + i * 16 + lr) * 32 + lhi * 8];
        #pragma unroll
        for (int j = 0; j < 4; ++j)
            bf[j] = *(const short8v*)&Bs[(wc * 64 + j * 16 + lr) * 32 + lhi * 8];
        #pragma unroll
        for (int i = 0; i < 4; ++i)
            #pragma unroll
            for (int j = 0; j < 4; ++j)
                acc[i][j] = __builtin_amdgcn_mfma_f32_16x16x32_bf16(af[i], bf[j], acc[i][j], 0, 0, 0);
    }
    #pragma unroll
    for (int i = 0; i < 4; ++i) {
        int row = m0 + wr * 64 + i * 16 + lhi * 4;
        #pragma unroll
        for (int j = 0; j < 4; ++j) {
            int col = n0 + wc * 64 + j * 16 + lr;
            float bv = bias[col];
            #pragma unroll
            for (int r = 0; r < 4; ++r)
                C[(row + r) * N + col] = acc[i][j][r] + bv;
        }
    }
}

// ---------------- LSTM recurrence: quarter-split (r10 measured-optimal) ----------------
// grid = 64 wgs (dir*32 + bs*4 + Q), 512 thr (8 waves x 32 permuted gate-cols).
// Wave cols = 2 tiles: {i,f}x8j, {g,o}x8j. Lane lr16<8 holds (i,g), lr16>=8
// holds (f,o) for hidden j = Q*64+wv*8+(lane&7). One shfl_xor(.,8) swaps
// row-halves so every lane computes gates for 2 rows. Exchange: r5 protocol,
// 3 peer quarters x 1 {tag|2xbf16} word per thread per step.
__global__ __launch_bounds__(512, 2)
void k_lstm(const float* __restrict__ xs_f, const float* __restrict__ xs_b,
            const unsigned short* __restrict__ whhp_f, const unsigned short* __restrict__ whhp_b,
            unsigned short* __restrict__ xout, unsigned long long* __restrict__ hx)
{
    const int tid  = threadIdx.x;
    const int wv   = tid >> 6, lane = tid & 63;
    const int lr16 = lane & 15, lh = lane >> 4;
    const int b3   = (lane >> 3) & 1, lr3 = lane & 7;
    const int wgid = blockIdx.x;            // dir*32 + bs*4 + Q
    const int dir  = wgid >> 5;
    const int bs   = (wgid >> 2) & 7;
    const int Q    = wgid & 3;
    const int b0   = bs * 16;
    const float* xs = dir ? xs_b : xs_f;
    const unsigned short* whhp = dir ? whhp_b : whhp_f;

    // B-frag preload: 2 tiles x 8 ks = 64 VGPRs
    const int ncol0 = Q * 256 + wv * 32 + lr16;     // tile0 col; tile1 = +16
    short8v wf[2][8];
    #pragma unroll
    for (int tt = 0; tt < 2; ++tt)
        #pragma unroll
        for (int ks = 0; ks < 8; ++ks)
            wf[tt][ks] = *(const short8v*)(whhp
                + (size_t)(ncol0 + tt * 16) * 256 + ks * 32 + lh * 8);

    __shared__ unsigned short At[2][16 * 256];      // [parity][row][j] bf16, swizzled

    const int grpbase = (dir * 8 + bs) * 4 * 1024;  // 4 quarter-wgs x 1024 words
    unsigned long long* hx_own = hx + grpbase + Q * 1024;

    const int jmine = Q * 64 + wv * 8 + lr3;        // my hidden index
    const int rowb  = 4 * lh;
    const int myr0  = rowb + 2 * b3;                // my 2 rows: myr0, myr0+1
    // unpack role: word w = tid of each peer -> (j_local, row pair)
    const int up_jl = (tid >> 6) * 8 + (tid & 7);
    const int up_r0 = 2 * ((tid >> 3) & 7);

    float c0 = 0.f, c1 = 0.f;
    float xv0[4], xv1[4];                           // x at my 2 cols, 4 rows
    {
        const int l0 = dir ? 127 : 0;
        #pragma unroll
        for (int r = 0; r < 4; ++r) {
            const float* xp = xs + ((size_t)(b0 + rowb + r) * 128 + l0) * 1024;
            xv0[r] = xp[ncol0];
            xv1[r] = xp[ncol0 + 16];
        }
    }

    for (int t = 0; t < 128; ++t) {
        const int l = dir ? (127 - t) : t;
        f32x4 acc0 = {}, acc1 = {};
        if (t > 0) {
            const char* Ab = (const char*)&At[(t - 1) & 1][0];
            #pragma unroll
            for (int ks = 0; ks < 8; ++ks) {
                int off = (lr16 * 512 + ks * 64 + lh * 16) ^ ((lr16 & 7) << 4);
                short8v a = *(const short8v*)(Ab + off);
                acc0 = __builtin_amdgcn_mfma_f32_16x16x32_bf16(a, wf[0][ks], acc0, 0, 0, 0);
                acc1 = __builtin_amdgcn_mfma_f32_16x16x32_bf16(a, wf[1][ks], acc1, 0, 0, 0);
            }
        }
        #pragma unroll
        for (int r = 0; r < 4; ++r) { acc0[r] += xv0[r]; acc1[r] += xv1[r]; }
        // swap row-halves with partner lane^8 (partner holds the other gate pair)
        float z0 = b3 ? acc0[0] : acc0[2];
        float z1 = b3 ? acc0[1] : acc0[3];
        float z2 = b3 ? acc1[0] : acc1[2];
        float z3 = b3 ? acc1[1] : acc1[3];
        float y0 = __shfl_xor(z0, 8);
        float y1 = __shfl_xor(z1, 8);
        float y2 = __shfl_xor(z2, 8);
        float y3 = __shfl_xor(z3, 8);
        float iv0 = b3 ? y0 : acc0[0], iv1 = b3 ? y1 : acc0[1];
        float fv0 = b3 ? acc0[2] : y0, fv1 = b3 ? acc0[3] : y1;
        float gv0 = b3 ? y2 : acc1[0], gv1 = b3 ? y3 : acc1[1];
        float ov0 = b3 ? acc1[2] : y2, ov1 = b3 ? acc1[3] : y3;
        // gates for my 2 rows
        iv0 = sigm_f(iv0); fv0 = sigm_f(fv0); gv0 = tanh_f(gv0); ov0 = sigm_f(ov0);
        c0 = fv0 * c0 + iv0 * gv0;
        float h0 = ov0 * tanh_f(c0);
        iv1 = sigm_f(iv1); fv1 = sigm_f(fv1); gv1 = tanh_f(gv1); ov1 = sigm_f(ov1);
        c1 = fv1 * c1 + iv1 * gv1;
        float h1 = ov1 * tanh_f(c1);
        unsigned short hb0 = f2bf(h0), hb1 = f2bf(h1);
        xout[((size_t)(b0 + myr0)     * 128 + l) * 512 + dir * 256 + jmine] = hb0;
        xout[((size_t)(b0 + myr0 + 1) * 128 + l) * 512 + dir * 256 + jmine] = hb1;

        if (t < 127) {
            const int p = t & 1;
            char* Aw = (char*)&At[p][0];
            {
                int r0_ = myr0, r1_ = myr0 + 1;
                *(unsigned short*)(Aw + ((r0_ * 512 + 2 * jmine) ^ ((r0_ & 7) << 4))) = hb0;
                *(unsigned short*)(Aw + ((r1_ * 512 + 2 * jmine) ^ ((r1_ & 7) << 4))) = hb1;
            }
            const unsigned tg = (unsigned)(t + 1);
            unsigned long long w = ((unsigned long long)tg << 32)
                                 | ((unsigned)hb0 | ((unsigned)hb1 << 16));
            __hip_atomic_store(hx_own + p * 512 + tid, w,
                               __ATOMIC_RELAXED, __HIP_MEMORY_SCOPE_AGENT);
            // prefetch xs(t+1)
            const int l2 = dir ? (126 - t) : (t + 1);
            #pragma unroll
            for (int r = 0; r < 4; ++r) {
                const float* xp = xs + ((size_t)(b0 + rowb + r) * 128 + l2) * 1024;
                xv0[r] = xp[ncol0];
                xv1[r] = xp[ncol0 + 16];
            }
            // poll 3 peer quarters (word w = tid each), unpack into At
            const unsigned long long* pp1 = hx + grpbase + (Q ^ 1) * 1024 + p * 512 + tid;
            const unsigned long long* pp2 = hx + grpbase + (Q ^ 2) * 1024 + p * 512 + tid;
            const unsigned long long* pp3 = hx + grpbase + (Q ^ 3) * 1024 + p * 512 + tid;
            unsigned long long u1 = __hip_atomic_load(pp1, __ATOMIC_RELAXED, __HIP_MEMORY_SCOPE_AGENT);
            unsigned long long u2 = __hip_atomic_load(pp2, __ATOMIC_RELAXED, __HIP_MEMORY_SCOPE_AGENT);
            unsigned long long u3 = __hip_atomic_load(pp3, __ATOMIC_RELAXED, __HIP_MEMORY_SCOPE_AGENT);
            while ((unsigned)(u1 >> 32) != tg)
                u1 = __hip_atomic_load(pp1, __ATOMIC_RELAXED, __HIP_MEMORY_SCOPE_AGENT);
            while ((unsigned)(u2 >> 32) != tg)
                u2 = __hip_atomic_load(pp2, __ATOMIC_RELAXED, __HIP_MEMORY_SCOPE_AGENT);
            while ((unsigned)(u3 >> 32) != tg)
                u3 = __hip_atomic_load(pp3, __ATOMIC_RELAXED, __HIP_MEMORY_SCOPE_AGENT);
            {
                int ra = up_r0, rb = up_r0 + 1;
                int j1 = (Q ^ 1) * 64 + up_jl;
                int j2 = (Q ^ 2) * 64 + up_jl;
                int j3 = (Q ^ 3) * 64 + up_jl;
                *(unsigned short*)(Aw + ((ra * 512 + 2 * j1) ^ ((ra & 7) << 4))) =
                    (unsigned short)(u1 & 0xffff);
                *(unsigned short*)(Aw + ((rb * 512 + 2 * j1) ^ ((rb & 7) << 4))) =
                    (unsigned short)((u1 >> 16) & 0xffff);
                *(unsigned short*)(Aw + ((ra * 512 + 2 * j2) ^ ((ra & 7) << 4))) =
                    (unsigned short)(u2 & 0xffff);
                *(unsigned short*)(Aw + ((rb * 512 + 2 * j2) ^ ((rb & 7) << 4))) =
                    (unsigned short)((u2 >> 16) & 0xffff);
                *(unsigned short*)(Aw + ((ra * 512 + 2 * j3) ^ ((ra & 7) << 4))) =
                    (unsigned short)(u3 & 0xffff);
                *(unsigned short*)(Aw + ((rb * 512 + 2 * j3) ^ ((rb & 7) << 4))) =
                    (unsigned short)((u3 >> 16) & 0xffff);
            }
            __syncthreads();
        }
    }
}

// ---------------- CSR build ----------------
__global__ void k_hist(const int* __restrict__ ei, int* __restrict__ deg) {
    int e = blockIdx.x * 256 + threadIdx.x;
    if (e >= EE) return;
    atomicAdd(&deg[ei[EE + e]], 1);
}

__global__ void k_scan(const int* __restrict__ deg, int* __restrict__ indptr) {
    __shared__ int sm[256];
    int tid = threadIdx.x;
    int b0 = tid * 64;
    int s = 0;
    for (int i = 0; i < 64; ++i) s += deg[b0 + i];
    sm[tid] = s;
    __syncthreads();
    for (int off = 1; off < 256; off <<= 1) {
        int v = (tid >= off) ? sm[tid - off] : 0;
        __syncthreads();
        sm[tid] += v;
        __syncthreads();
    }
    int run = sm[tid] - s;   // exclusive prefix
    for (int i = 0; i < 64; ++i) { indptr[b0 + i] = run; run += deg[b0 + i]; }
    if (tid == 255) indptr[NN] = run;
}

__global__ void k_scatter(const int* __restrict__ ei, const int* __restrict__ indptr,
                          int* __restrict__ fill, int* __restrict__ cols) {
    int e = blockIdx.x * 256 + threadIdx.x;
    if (e >= EE) return;
    int d = ei[EE + e];
    int slot = atomicAdd(&fill[d], 1);
    cols[indptr[d] + slot] = ei[e];
}

// ---------------- SAGE gather, graph-local via LDS ----------------
// Edges connect nodes within one graph (edge_index = el + gid*L by
// construction). wg = (graph, half): stage the graph's 128 rows (128 KB bf16)
// into LDS coalesced, then each wave aggregates dst nodes reading neighbors
// from LDS. Accumulation order per dst = CSR order -> bit-identical output.
__global__ __launch_bounds__(512)
void k_gather_lds(const unsigned short* __restrict__ x, const int* __restrict__ indptr,
                  const int* __restrict__ cols, unsigned short* __restrict__ catb)
{
    extern __shared__ char gsm[];
    unsigned short* Xs = (unsigned short*)gsm;     // [128][512] bf16 = 128 KB
    const int tid  = threadIdx.x;
    const int g    = blockIdx.x >> 1;
    const int hf   = blockIdx.x & 1;
    const int base = g * 128;
    {   // stage: 131072 B = 512 thr x 16 B x 16 iters, fully coalesced
        const unsigned short* src = x + (size_t)base * 512;
        #pragma unroll
        for (int it = 0; it < 16; ++it) {
            int i = it * 512 + tid;                // 16B-chunk index; 64 chunks/row
            int row = i >> 6, c = (i & 63) * 8;
            *(short8v*)(Xs + row * 512 + c) = *(const short8v*)(src + (size_t)row * 512 + c);
        }
    }
    __syncthreads();
    const int wv = tid >> 6, lane = tid & 63;
    for (int rr = 0; rr < 8; ++rr) {
        int node = base + hf * 64 + rr * 8 + wv;
        int s = indptr[node], e = indptr[node + 1];
        float a[8] = {};
        for (int p = s; p < e; ++p) {
            int lrow = cols[p] - base;             // local row in [0,128)
            short8v v = *(const short8v*)(Xs + lrow * 512 + lane * 8);
            #pragma unroll
            for (int q = 0; q < 8; ++q) a[q] += bf2f((unsigned short)v[q]);
        }
        float sc = 1.f / (float)((e - s) > 1 ? (e - s) : 1);
        unsigned short o[8];
        #pragma unroll
        for (int q = 0; q < 8; ++q) o[q] = f2bf(a[q] * sc);
        unsigned short* cp = catb + (size_t)node * 1024 + lane * 8;
        *(short8v*)cp = *(short8v*)o;
        *(short8v*)(cp + 512) = *(const short8v*)(Xs + (node - base) * 512 + lane * 8);
    }
}

// ---------------- row L2-normalize + relu: fp32 in -> bf16 out ----------------
__global__ __launch_bounds__(256)
void k_norm_relu_bf(const float* __restrict__ y, unsigned short* __restrict__ o)
{
    int gw = (blockIdx.x * 256 + threadIdx.x) >> 6;
    int lane = threadIdx.x & 63;
    if (gw >= NN) return;
    const float* row = y + gw * 512 + lane * 8;
    float4 v0 = *(const float4*)row;
    float4 v1 = *(const float4*)(row + 4);
    float ss = v0.x*v0.x + v0.y*v0.y + v0.z*v0.z + v0.w*v0.w
             + v1.x*v1.x + v1.y*v1.y + v1.z*v1.z + v1.w*v1.w;
    #pragma unroll
    for (int off = 32; off >= 1; off >>= 1) ss += __shfl_xor(ss, off);
    float sc = 1.f / fmaxf(sqrtf(ss), 1e-12f);
    unsigned short ob[8];
    ob[0] = f2bf(fmaxf(v0.x*sc, 0.f)); ob[1] = f2bf(fmaxf(v0.y*sc, 0.f));
    ob[2] = f2bf(fmaxf(v0.z*sc, 0.f)); ob[3] = f2bf(fmaxf(v0.w*sc, 0.f));
    ob[4] = f2bf(fmaxf(v1.x*sc, 0.f)); ob[5] = f2bf(fmaxf(v1.y*sc, 0.f));
    ob[6] = f2bf(fmaxf(v1.z*sc, 0.f)); ob[7] = f2bf(fmaxf(v1.w*sc, 0.f));
    *(short8v*)(o + gw * 512 + lane * 8) = *(short8v*)ob;
}

// ---------------- mean-pool per graph + linear head (bf16 in) ----------------
__global__ __launch_bounds__(256)
void k_pool_bf(const unsigned short* __restrict__ x, const float* __restrict__ Wlin,
               const float* __restrict__ blin, float* __restrict__ out)
{
    int g = blockIdx.x;
    int tid = threadIdx.x;
    const unsigned short* base = x + (size_t)g * 128 * 512;
    float a0 = 0.f, a1 = 0.f;
    for (int r = 0; r < 128; ++r) {
        unsigned v = *(const unsigned*)(base + r * 512 + 2 * tid);
        a0 += bf2f((unsigned short)(v & 0xffff));
        a1 += bf2f((unsigned short)(v >> 16));
    }
    __shared__ float pooled[512];
    pooled[2*tid]     = a0 * (1.f / 128.f);
    pooled[2*tid + 1] = a1 * (1.f / 128.f);
    __syncthreads();
    if (tid < 64) {
        float p0 = 0.f, p1 = 0.f;
        for (int k = tid; k < 512; k += 64) {
            float pv = pooled[k];
            p0 += pv * Wlin[2*k];
            p1 += pv * Wlin[2*k + 1];
        }
        #pragma unroll
        for (int off = 32; off >= 1; off >>= 1) {
            p0 += __shfl_xor(p0, off);
            p1 += __shfl_xor(p1, off);
        }
        if (tid == 0) {
            out[2*g]     = p0 + blin[0];
            out[2*g + 1] = p1 + blin[1];
        }
    }
}

extern "C" void kernel_launch(void* const* d_in, const int* in_sizes, int n_in,
                              void* d_out, int out_size, void* d_ws, size_t ws_size,
                              hipStream_t stream)
{
    (void)in_sizes; (void)n_in; (void)out_size; (void)ws_size;
    const int*   word_seq = (const int*)  d_in[0];
    const int*   ei       = (const int*)  d_in[1];
    const float* tab      = (const float*)d_in[3];
    const float* wih_f    = (const float*)d_in[4];
    const float* whh_f    = (const float*)d_in[5];
    const float* b_f      = (const float*)d_in[6];
    const float* wih_b    = (const float*)d_in[7];
    const float* whh_b    = (const float*)d_in[8];
    const float* b_b      = (const float*)d_in[9];
    const float* Wl1      = (const float*)d_in[10];
    const float* Wr1      = (const float*)d_in[11];
    const float* b1       = (const float*)d_in[12];
    const float* Wl2      = (const float*)d_in[13];
    const float* Wr2      = (const float*)d_in[14];
    const float* b2       = (const float*)d_in[15];
    const float* Wl3      = (const float*)d_in[16];
    const float* Wr3      = (const float*)d_in[17];
    const float* b3       = (const float*)d_in[18];
    const float* Wlin     = (const float*)d_in[19];
    const float* blin     = (const float*)d_in[20];
    float* out = (float*)d_out;

    char* w = (char*)d_ws;
    int*   deg    = (int*)  (w);                     //     65,536
    int*   indptr = (int*)  (w + 65536);             //     66,048
    int*   fill   = (int*)  (w + 131584);            //     65,536
    int*   cols   = (int*)  (w + 197120);            //  1,048,576
    unsigned long long* hx = (unsigned long long*)(w + 1245696);   // 524,288
    unsigned short* whhp_f = (unsigned short*)(w + 1769984);       // 524,288
    unsigned short* whhp_b = (unsigned short*)(w + 2294272);       // 524,288
    float* pb_f   = (float*)(w + 2818560);           //      4,096
    float* pb_b   = (float*)(w + 2822656);           //      4,096
    unsigned short* wt_f = (unsigned short*)(w + 2826752);   // 655,360
    unsigned short* wt_b = (unsigned short*)(w + 3482112);   // 655,360
    unsigned short* wc1  = (unsigned short*)(w + 4137472);   // 1,048,576
    unsigned short* wc2  = (unsigned short*)(w + 5186048);   // 1,048,576
    unsigned short* wc3  = (unsigned short*)(w + 6234624);   // 1,048,576
    unsigned short* xeb  = (unsigned short*)(w + 7283200);   // 10,485,760
    float* xs_f   = (float*)(w + 17768960);          // 67,108,864
    float* xs_b   = (float*)(w + 84877824);          // 67,108,864
    unsigned short* x0b = (unsigned short*)(w + 151986688);  // 16,777,216 (end ~161 MB)
    // post-LSTM reuse of xs regions:
    unsigned short* catb = (unsigned short*)(w + 17768960);  // 32 MB in xs_f
    float* x1     = (float*)(w + 51323392);          // 32 MB in xs_f
    unsigned short* xb_a = (unsigned short*)(w + 84877824);  // 16 MB in xs_b
    unsigned short* xb_b = (unsigned short*)(w + 101655040); // 16 MB in xs_b

    // conversions + embedding (bf16, vectorized 16B/thread)
    k_embed_bf<<<2560, 256, 0, stream>>>(word_seq, tab, xeb);
    k_cvt_wih<<<160, 256, 0, stream>>>(wih_f, wt_f);
    k_cvt_wih<<<160, 256, 0, stream>>>(wih_b, wt_b);
    k_cvt_whh<<<128, 256, 0, stream>>>(whh_f, whhp_f);
    k_cvt_whh<<<128, 256, 0, stream>>>(whh_b, whhp_b);
    k_permb<<<4, 256, 0, stream>>>(b_f, pb_f);
    k_permb<<<4, 256, 0, stream>>>(b_b, pb_b);
    k_cvt_wcat<<<2048, 256, 0, stream>>>(Wl1, Wr1, wc1);
    k_cvt_wcat<<<2048, 256, 0, stream>>>(Wl2, Wr2, wc2);
    k_cvt_wcat<<<2048, 256, 0, stream>>>(Wl3, Wr3, wc3);

    // CSR build + hx tag clear
    k_init<<<256, 256, 0, stream>>>(hx, deg, fill);
    k_hist<<<1024, 256, 0, stream>>>(ei, deg);
    k_scan<<<1, 256, 0, stream>>>(deg, indptr);
    k_scatter<<<1024, 256, 0, stream>>>(ei, indptr, fill, cols);

    // LSTM input projections (bf16 MFMA): xs = xeb @ wt^T + pb (permuted cols)
    k_mgemm<<<dim3(128, 8), 256, 0, stream>>>(xeb, wt_f, pb_f, xs_f, 1024, 320);
    k_mgemm<<<dim3(128, 8), 256, 0, stream>>>(xeb, wt_b, pb_b, xs_b, 1024, 320);

    // bidirectional LSTM scan -> x0b = [hf | hb] (bf16)
    k_lstm<<<64, 512, 0, stream>>>(xs_f, xs_b, whhp_f, whhp_b, x0b, hx);

    // SAGE layer 1
    k_gather_lds<<<256, 512, 131072, stream>>>(x0b, indptr, cols, catb);
    k_mgemm<<<dim3(128, 4), 256, 0, stream>>>(catb, wc1, b1, x1, 512, 1024);
    k_norm_relu_bf<<<4096, 256, 0, stream>>>(x1, xb_a);
    // SAGE layer 2
    k_gather_lds<<<256, 512, 131072, stream>>>(xb_a, indptr, cols, catb);
    k_mgemm<<<dim3(128, 4), 256, 0, stream>>>(catb, wc2, b2, x1, 512, 1024);
    k_norm_relu_bf<<<4096, 256, 0, stream>>>(x1, xb_b);
    // SAGE layer 3
    k_gather_lds<<<256, 512, 131072, stream>>>(xb_b, indptr, cols, catb);
    k_mgemm<<<dim3(128, 4), 256, 0, stream>>>(catb, wc3, b3, x1, 512, 1024);
    k_norm_relu_bf<<<4096, 256, 0, stream>>>(x1, xb_a);

    // mean pool per graph + linear head
    k_pool_bf<<<128, 256, 0, stream>>>(xb_a, Wlin, blin, out);
}

// Round 16
// 639.974 us; speedup vs baseline: 1.2671x; 1.0028x over previous
//
#include <hip/hip_runtime.h>
#include <math.h>

#define NN   16384
#define EE   262144

typedef __attribute__((ext_vector_type(8))) short  short8v;   // 8 bf16 = 4 VGPR
typedef __attribute__((ext_vector_type(4))) float  f32x4;

__device__ inline unsigned short f2bf(float f) {
    union { float f; unsigned u; } v; v.f = f;
    unsigned r = v.u + 0x7fff + ((v.u >> 16) & 1);   // RNE
    return (unsigned short)(r >> 16);
}
__device__ inline float bf2f(unsigned short b) {
    unsigned u = ((unsigned)b) << 16;
    union { unsigned u; float f; } v; v.u = u; return v.f;
}
__device__ inline float sigm_f(float x) { return 1.f / (1.f + __expf(-x)); }
__device__ inline float tanh_f(float x) {
    x = fminf(15.f, fmaxf(-15.f, x));
    float e = __expf(2.f * x);
    return (e - 1.f) / (e + 1.f);
}
// quarter-split gate-col permutation:
// n'' = Q*256 + wv*32 + tile*16 + tc,  tile in {0,1}, tc in [0,16)
// gate g = tile*2 + (tc>>3), hidden j = Q*64 + wv*8 + (tc&7), orig = g*256 + j
__device__ inline int gate_orig2(int np) {
    int Q = np >> 8, wv = (np >> 5) & 7, tile = (np >> 4) & 1, tc = np & 15;
    int g = tile * 2 + (tc >> 3);
    int j = Q * 64 + wv * 8 + (tc & 7);
    return g * 256 + j;
}

// ---------------- init (zero hx tags / deg / fill) ----------------
__global__ void k_init(unsigned long long* __restrict__ hx, int* __restrict__ deg,
                       int* __restrict__ fill) {
    int i = blockIdx.x * 256 + threadIdx.x;
    if (i < 65536) hx[i] = 0ull;            // tag=0 matches no wanted tag (>=1)
    if (i < NN) { deg[i] = 0; fill[i] = 0; }
}

// ---------------- embedding gather -> bf16, K padded 300->320 (vectorized 16B/thr) ----------------
__global__ void k_embed_bf(const int* __restrict__ wseq, const float* __restrict__ tab,
                           unsigned short* __restrict__ xeb) {
    int i = blockIdx.x * 256 + threadIdx.x;          // chunk of 8 elems
    if (i >= NN * 40) return;
    int row = i / 40, c8 = i - row * 40;
    int k = c8 * 8;
    unsigned short o[8];
    const float* tp = tab + (size_t)wseq[row] * 300;  // row base: 1200 B (16B aligned)
    if (k + 8 <= 300) {
        float4 v0 = *(const float4*)(tp + k);
        float4 v1 = *(const float4*)(tp + k + 4);
        o[0]=f2bf(v0.x); o[1]=f2bf(v0.y); o[2]=f2bf(v0.z); o[3]=f2bf(v0.w);
        o[4]=f2bf(v1.x); o[5]=f2bf(v1.y); o[6]=f2bf(v1.z); o[7]=f2bf(v1.w);
    } else {
        #pragma unroll
        for (int q = 0; q < 8; ++q) {
            int kk = k + q;
            o[q] = f2bf(kk < 300 ? tp[kk] : 0.f);
        }
    }
    *(short8v*)(xeb + (size_t)row * 320 + k) = *(short8v*)o;
}

// ---------------- weight conversions (gate_orig2 permutation, vectorized) ----------------
__global__ void k_cvt_wih(const float* __restrict__ wih, unsigned short* __restrict__ wt) {
    int i = blockIdx.x * 256 + threadIdx.x;
    if (i >= 1024 * 40) return;
    int np = i / 40, c8 = i - np * 40;
    int k = c8 * 8;
    const float* src = wih + (size_t)gate_orig2(np) * 300;   // 1200 B rows, 16B aligned
    unsigned short o[8];
    if (k + 8 <= 300) {
        float4 v0 = *(const float4*)(src + k);
        float4 v1 = *(const float4*)(src + k + 4);
        o[0]=f2bf(v0.x); o[1]=f2bf(v0.y); o[2]=f2bf(v0.z); o[3]=f2bf(v0.w);
        o[4]=f2bf(v1.x); o[5]=f2bf(v1.y); o[6]=f2bf(v1.z); o[7]=f2bf(v1.w);
    } else {
        #pragma unroll
        for (int q = 0; q < 8; ++q) {
            int kk = k + q;
            o[q] = f2bf(kk < 300 ? src[kk] : 0.f);
        }
    }
    *(short8v*)(wt + (size_t)np * 320 + k) = *(short8v*)o;
}
__global__ void k_cvt_whh(const float* __restrict__ whh, unsigned short* __restrict__ wp) {
    int i = blockIdx.x * 256 + threadIdx.x;
    if (i >= 1024 * 32) return;
    int np = i >> 5, kc = i & 31;
    int k = kc * 8;
    const float* src = whh + (size_t)gate_orig2(np) * 256 + k;  // 1024 B rows
    float4 v0 = *(const float4*)src;
    float4 v1 = *(const float4*)(src + 4);
    unsigned short o[8];
    o[0]=f2bf(v0.x); o[1]=f2bf(v0.y); o[2]=f2bf(v0.z); o[3]=f2bf(v0.w);
    o[4]=f2bf(v1.x); o[5]=f2bf(v1.y); o[6]=f2bf(v1.z); o[7]=f2bf(v1.w);
    *(short8v*)(wp + (size_t)np * 256 + k) = *(short8v*)o;
}
__global__ void k_permb(const float* __restrict__ b, float* __restrict__ pb) {
    int i = blockIdx.x * 256 + threadIdx.x;
    if (i < 1024) pb[i] = b[gate_orig2(i)];
}
__global__ void k_cvt_wcat(const float* __restrict__ Wl, const float* __restrict__ Wr,
                           unsigned short* __restrict__ wc) {
    int i = blockIdx.x * 256 + threadIdx.x;
    if (i >= 512 * 1024) return;
    int n = i >> 10, k = i & 1023;
    float f = (k < 512) ? Wl[k * 512 + n] : Wr[(k - 512) * 512 + n];
    wc[i] = f2bf(f);
}

// ---------------- bf16 MFMA GEMM: C[M][N] = A[M][Ka] * Bt[N][Ka]^T + bias ----------------
__global__ __launch_bounds__(256)
void k_mgemm(const unsigned short* __restrict__ A, const unsigned short* __restrict__ Bt,
             const float* __restrict__ bias, float* __restrict__ C, int N, int Ka)
{
    __shared__ unsigned short As[128 * 32];
    __shared__ unsigned short Bs[128 * 32];
    const int tid = threadIdx.x;
    const int m0 = blockIdx.x << 7, n0 = blockIdx.y << 7;
    const int w = tid >> 6, lane = tid & 63;
    const int wr = w >> 1, wc = w & 1;
    const int lr = lane & 15, lhi = lane >> 4;
    const int r0 = tid >> 2, kc0 = (tid & 3) * 8;

    f32x4 acc[4][4] = {};

    for (int k0 = 0; k0 < Ka; k0 += 32) {
        short8v a0 = *(const short8v*)(A + (m0 + r0) * Ka + k0 + kc0);
        short8v a1 = *(const short8v*)(A + (m0 + 64 + r0) * Ka + k0 + kc0);
        short8v b0 = *(const short8v*)(Bt + (n0 + r0) * Ka + k0 + kc0);
        short8v b1 = *(const short8v*)(Bt + (n0 + 64 + r0) * Ka + k0 + kc0);
        __syncthreads();
        *(short8v*)&As[r0 * 32 + kc0]        = a0;
        *(short8v*)&As[(64 + r0) * 32 + kc0] = a1;
        *(short8v*)&Bs[r0 * 32 + kc0]        = b0;
        *(short8v*)&Bs[(64 + r0) * 32 + kc0] = b1;
        __syncthreads();
        short8v af[4], bf[4];
        #pragma unroll
        for (int i = 0; i < 4; ++i)
            af[i] = *(const short8v*)&As[(wr * 64 + i * 16 + lr) * 32 + lhi * 8];
        #pragma unroll
        for (int j = 0; j < 4; ++j)
            bf[j] = *(const short8v*)&Bs[(wc * 64 + j * 16 + lr) * 32 + lhi * 8];
        #pragma unroll
        for (int i = 0; i < 4; ++i)
            #pragma unroll
            for (int j = 0; j < 4; ++j)
                acc[i][j] = __builtin_amdgcn_mfma_f32_16x16x32_bf16(af[i], bf[j], acc[i][j], 0, 0, 0);
    }
    #pragma unroll
    for (int i = 0; i < 4; ++i) {
        int row = m0 + wr * 64 + i * 16 + lhi * 4;
        #pragma unroll
        for (int j = 0; j < 4; ++j) {
            int col = n0 + wc * 64 + j * 16 + lr;
            float bv = bias[col];
            #pragma unroll
            for (int r = 0; r < 4; ++r)
                C[(row + r) * N + col] = acc[i][j][r] + bv;
        }
    }
}

// ---------------- LSTM recurrence: quarter-split, occupancy pinned to 2 waves/EU ----------------
// r10 structure. amdgpu_waves_per_eu(2,2) tells the allocator occupancy is
// FIXED at 2 waves/SIMD -> no benefit to economizing registers -> wf[2][8]
// (64 VGPRs) should finally stay resident instead of being rematerialized
// from L2 every step (r10: VGPR=68, FETCH 116MB, ~1us/step refetch).
__global__ __attribute__((amdgpu_waves_per_eu(2, 2))) __launch_bounds__(512)
void k_lstm(const float* __restrict__ xs_f, const float* __restrict__ xs_b,
            const unsigned short* __restrict__ whhp_f, const unsigned short* __restrict__ whhp_b,
            unsigned short* __restrict__ xout, unsigned long long* __restrict__ hx)
{
    const int tid  = threadIdx.x;
    const int wv   = tid >> 6, lane = tid & 63;
    const int lr16 = lane & 15, lh = lane >> 4;
    const int b3   = (lane >> 3) & 1, lr3 = lane & 7;
    const int wgid = blockIdx.x;            // dir*32 + bs*4 + Q
    const int dir  = wgid >> 5;
    const int bs   = (wgid >> 2) & 7;
    const int Q    = wgid & 3;
    const int b0   = bs * 16;
    const float* xs = dir ? xs_b : xs_f;
    const unsigned short* whhp = dir ? whhp_b : whhp_f;

    // B-frag preload: 2 tiles x 8 ks = 64 VGPRs
    const int ncol0 = Q * 256 + wv * 32 + lr16;     // tile0 col; tile1 = +16
    short8v wf[2][8];
    #pragma unroll
    for (int tt = 0; tt < 2; ++tt)
        #pragma unroll
        for (int ks = 0; ks < 8; ++ks)
            wf[tt][ks] = *(const short8v*)(whhp
                + (size_t)(ncol0 + tt * 16) * 256 + ks * 32 + lh * 8);

    __shared__ unsigned short At[2][16 * 256];      // [parity][row][j] bf16, swizzled

    const int grpbase = (dir * 8 + bs) * 4 * 1024;  // 4 quarter-wgs x 1024 words
    unsigned long long* hx_own = hx + grpbase + Q * 1024;

    const int jmine = Q * 64 + wv * 8 + lr3;        // my hidden index
    const int rowb  = 4 * lh;
    const int myr0  = rowb + 2 * b3;                // my 2 rows: myr0, myr0+1
    // unpack role: word w = tid of each peer -> (j_local, row pair)
    const int up_jl = (tid >> 6) * 8 + (tid & 7);
    const int up_r0 = 2 * ((tid >> 3) & 7);

    float c0 = 0.f, c1 = 0.f;
    float xv0[4], xv1[4];                           // x at my 2 cols, 4 rows
    {
        const int l0 = dir ? 127 : 0;
        #pragma unroll
        for (int r = 0; r < 4; ++r) {
            const float* xp = xs + ((size_t)(b0 + rowb + r) * 128 + l0) * 1024;
            xv0[r] = xp[ncol0];
            xv1[r] = xp[ncol0 + 16];
        }
    }

    for (int t = 0; t < 128; ++t) {
        const int l = dir ? (127 - t) : t;
        f32x4 acc0 = {}, acc1 = {};
        if (t > 0) {
            const char* Ab = (const char*)&At[(t - 1) & 1][0];
            #pragma unroll
            for (int ks = 0; ks < 8; ++ks) {
                int off = (lr16 * 512 + ks * 64 + lh * 16) ^ ((lr16 & 7) << 4);
                short8v a = *(const short8v*)(Ab + off);
                acc0 = __builtin_amdgcn_mfma_f32_16x16x32_bf16(a, wf[0][ks], acc0, 0, 0, 0);
                acc1 = __builtin_amdgcn_mfma_f32_16x16x32_bf16(a, wf[1][ks], acc1, 0, 0, 0);
            }
        }
        #pragma unroll
        for (int r = 0; r < 4; ++r) { acc0[r] += xv0[r]; acc1[r] += xv1[r]; }
        // swap row-halves with partner lane^8 (partner holds the other gate pair)
        float z0 = b3 ? acc0[0] : acc0[2];
        float z1 = b3 ? acc0[1] : acc0[3];
        float z2 = b3 ? acc1[0] : acc1[2];
        float z3 = b3 ? acc1[1] : acc1[3];
        float y0 = __shfl_xor(z0, 8);
        float y1 = __shfl_xor(z1, 8);
        float y2 = __shfl_xor(z2, 8);
        float y3 = __shfl_xor(z3, 8);
        float iv0 = b3 ? y0 : acc0[0], iv1 = b3 ? y1 : acc0[1];
        float fv0 = b3 ? acc0[2] : y0, fv1 = b3 ? acc0[3] : y1;
        float gv0 = b3 ? y2 : acc1[0], gv1 = b3 ? y3 : acc1[1];
        float ov0 = b3 ? acc1[2] : y2, ov1 = b3 ? acc1[3] : y3;
        // gates for my 2 rows
        iv0 = sigm_f(iv0); fv0 = sigm_f(fv0); gv0 = tanh_f(gv0); ov0 = sigm_f(ov0);
        c0 = fv0 * c0 + iv0 * gv0;
        float h0 = ov0 * tanh_f(c0);
        iv1 = sigm_f(iv1); fv1 = sigm_f(fv1); gv1 = tanh_f(gv1); ov1 = sigm_f(ov1);
        c1 = fv1 * c1 + iv1 * gv1;
        float h1 = ov1 * tanh_f(c1);
        unsigned short hb0 = f2bf(h0), hb1 = f2bf(h1);
        xout[((size_t)(b0 + myr0)     * 128 + l) * 512 + dir * 256 + jmine] = hb0;
        xout[((size_t)(b0 + myr0 + 1) * 128 + l) * 512 + dir * 256 + jmine] = hb1;

        if (t < 127) {
            const int p = t & 1;
            char* Aw = (char*)&At[p][0];
            {
                int r0_ = myr0, r1_ = myr0 + 1;
                *(unsigned short*)(Aw + ((r0_ * 512 + 2 * jmine) ^ ((r0_ & 7) << 4))) = hb0;
                *(unsigned short*)(Aw + ((r1_ * 512 + 2 * jmine) ^ ((r1_ & 7) << 4))) = hb1;
            }
            const unsigned tg = (unsigned)(t + 1);
            unsigned long long w = ((unsigned long long)tg << 32)
                                 | ((unsigned)hb0 | ((unsigned)hb1 << 16));
            __hip_atomic_store(hx_own + p * 512 + tid, w,
                               __ATOMIC_RELAXED, __HIP_MEMORY_SCOPE_AGENT);
            // prefetch xs(t+1)
            const int l2 = dir ? (126 - t) : (t + 1);
            #pragma unroll
            for (int r = 0; r < 4; ++r) {
                const float* xp = xs + ((size_t)(b0 + rowb + r) * 128 + l2) * 1024;
                xv0[r] = xp[ncol0];
                xv1[r] = xp[ncol0 + 16];
            }
            // poll 3 peer quarters (word w = tid each), unpack into At
            const unsigned long long* pp1 = hx + grpbase + (Q ^ 1) * 1024 + p * 512 + tid;
            const unsigned long long* pp2 = hx + grpbase + (Q ^ 2) * 1024 + p * 512 + tid;
            const unsigned long long* pp3 = hx + grpbase + (Q ^ 3) * 1024 + p * 512 + tid;
            unsigned long long u1 = __hip_atomic_load(pp1, __ATOMIC_RELAXED, __HIP_MEMORY_SCOPE_AGENT);
            unsigned long long u2 = __hip_atomic_load(pp2, __ATOMIC_RELAXED, __HIP_MEMORY_SCOPE_AGENT);
            unsigned long long u3 = __hip_atomic_load(pp3, __ATOMIC_RELAXED, __HIP_MEMORY_SCOPE_AGENT);
            while ((unsigned)(u1 >> 32) != tg)
                u1 = __hip_atomic_load(pp1, __ATOMIC_RELAXED, __HIP_MEMORY_SCOPE_AGENT);
            while ((unsigned)(u2 >> 32) != tg)
                u2 = __hip_atomic_load(pp2, __ATOMIC_RELAXED, __HIP_MEMORY_SCOPE_AGENT);
            while ((unsigned)(u3 >> 32) != tg)
                u3 = __hip_atomic_load(pp3, __ATOMIC_RELAXED, __HIP_MEMORY_SCOPE_AGENT);
            {
                int ra = up_r0, rb = up_r0 + 1;
                int j1 = (Q ^ 1) * 64 + up_jl;
                int j2 = (Q ^ 2) * 64 + up_jl;
                int j3 = (Q ^ 3) * 64 + up_jl;
                *(unsigned short*)(Aw + ((ra * 512 + 2 * j1) ^ ((ra & 7) << 4))) =
                    (unsigned short)(u1 & 0xffff);
                *(unsigned short*)(Aw + ((rb * 512 + 2 * j1) ^ ((rb & 7) << 4))) =
                    (unsigned short)((u1 >> 16) & 0xffff);
                *(unsigned short*)(Aw + ((ra * 512 + 2 * j2) ^ ((ra & 7) << 4))) =
                    (unsigned short)(u2 & 0xffff);
                *(unsigned short*)(Aw + ((rb * 512 + 2 * j2) ^ ((rb & 7) << 4))) =
                    (unsigned short)((u2 >> 16) & 0xffff);
                *(unsigned short*)(Aw + ((ra * 512 + 2 * j3) ^ ((ra & 7) << 4))) =
                    (unsigned short)(u3 & 0xffff);
                *(unsigned short*)(Aw + ((rb * 512 + 2 * j3) ^ ((rb & 7) << 4))) =
                    (unsigned short)((u3 >> 16) & 0xffff);
            }
            __syncthreads();
        }
    }
}

// ---------------- CSR build ----------------
__global__ void k_hist(const int* __restrict__ ei, int* __restrict__ deg) {
    int e = blockIdx.x * 256 + threadIdx.x;
    if (e >= EE) return;
    atomicAdd(&deg[ei[EE + e]], 1);
}

__global__ void k_scan(const int* __restrict__ deg, int* __restrict__ indptr) {
    __shared__ int sm[256];
    int tid = threadIdx.x;
    int b0 = tid * 64;
    int s = 0;
    for (int i = 0; i < 64; ++i) s += deg[b0 + i];
    sm[tid] = s;
    __syncthreads();
    for (int off = 1; off < 256; off <<= 1) {
        int v = (tid >= off) ? sm[tid - off] : 0;
        __syncthreads();
        sm[tid] += v;
        __syncthreads();
    }
    int run = sm[tid] - s;   // exclusive prefix
    for (int i = 0; i < 64; ++i) { indptr[b0 + i] = run; run += deg[b0 + i]; }
    if (tid == 255) indptr[NN] = run;
}

__global__ void k_scatter(const int* __restrict__ ei, const int* __restrict__ indptr,
                          int* __restrict__ fill, int* __restrict__ cols) {
    int e = blockIdx.x * 256 + threadIdx.x;
    if (e >= EE) return;
    int d = ei[EE + e];
    int slot = atomicAdd(&fill[d], 1);
    cols[indptr[d] + slot] = ei[e];
}

// ---------------- SAGE gather, graph-local via LDS ----------------
// Edges connect nodes within one graph (edge_index = el + gid*L by
// construction). wg = (graph, half): stage the graph's 128 rows (128 KB bf16)
// into LDS coalesced, then each wave aggregates dst nodes reading neighbors
// from LDS. Accumulation order per dst = CSR order -> bit-identical output.
__global__ __launch_bounds__(512)
void k_gather_lds(const unsigned short* __restrict__ x, const int* __restrict__ indptr,
                  const int* __restrict__ cols, unsigned short* __restrict__ catb)
{
    extern __shared__ char gsm[];
    unsigned short* Xs = (unsigned short*)gsm;     // [128][512] bf16 = 128 KB
    const int tid  = threadIdx.x;
    const int g    = blockIdx.x >> 1;
    const int hf   = blockIdx.x & 1;
    const int base = g * 128;
    {   // stage: 131072 B = 512 thr x 16 B x 16 iters, fully coalesced
        const unsigned short* src = x + (size_t)base * 512;
        #pragma unroll
        for (int it = 0; it < 16; ++it) {
            int i = it * 512 + tid;                // 16B-chunk index; 64 chunks/row
            int row = i >> 6, c = (i & 63) * 8;
            *(short8v*)(Xs + row * 512 + c) = *(const short8v*)(src + (size_t)row * 512 + c);
        }
    }
    __syncthreads();
    const int wv = tid >> 6, lane = tid & 63;
    for (int rr = 0; rr < 8; ++rr) {
        int node = base + hf * 64 + rr * 8 + wv;
        int s = indptr[node], e = indptr[node + 1];
        float a[8] = {};
        for (int p = s; p < e; ++p) {
            int lrow = cols[p] - base;             // local row in [0,128)
            short8v v = *(const short8v*)(Xs + lrow * 512 + lane * 8);
            #pragma unroll
            for (int q = 0; q < 8; ++q) a[q] += bf2f((unsigned short)v[q]);
        }
        float sc = 1.f / (float)((e - s) > 1 ? (e - s) : 1);
        unsigned short o[8];
        #pragma unroll
        for (int q = 0; q < 8; ++q) o[q] = f2bf(a[q] * sc);
        unsigned short* cp = catb + (size_t)node * 1024 + lane * 8;
        *(short8v*)cp = *(short8v*)o;
        *(short8v*)(cp + 512) = *(const short8v*)(Xs + (node - base) * 512 + lane * 8);
    }
}

// ---------------- row L2-normalize + relu: fp32 in -> bf16 out ----------------
__global__ __launch_bounds__(256)
void k_norm_relu_bf(const float* __restrict__ y, unsigned short* __restrict__ o)
{
    int gw = (blockIdx.x * 256 + threadIdx.x) >> 6;
    int lane = threadIdx.x & 63;
    if (gw >= NN) return;
    const float* row = y + gw * 512 + lane * 8;
    float4 v0 = *(const float4*)row;
    float4 v1 = *(const float4*)(row + 4);
    float ss = v0.x*v0.x + v0.y*v0.y + v0.z*v0.z + v0.w*v0.w
             + v1.x*v1.x + v1.y*v1.y + v1.z*v1.z + v1.w*v1.w;
    #pragma unroll
    for (int off = 32; off >= 1; off >>= 1) ss += __shfl_xor(ss, off);
    float sc = 1.f / fmaxf(sqrtf(ss), 1e-12f);
    unsigned short ob[8];
    ob[0] = f2bf(fmaxf(v0.x*sc, 0.f)); ob[1] = f2bf(fmaxf(v0.y*sc, 0.f));
    ob[2] = f2bf(fmaxf(v0.z*sc, 0.f)); ob[3] = f2bf(fmaxf(v0.w*sc, 0.f));
    ob[4] = f2bf(fmaxf(v1.x*sc, 0.f)); ob[5] = f2bf(fmaxf(v1.y*sc, 0.f));
    ob[6] = f2bf(fmaxf(v1.z*sc, 0.f)); ob[7] = f2bf(fmaxf(v1.w*sc, 0.f));
    *(short8v*)(o + gw * 512 + lane * 8) = *(short8v*)ob;
}

// ---------------- mean-pool per graph + linear head (bf16 in) ----------------
__global__ __launch_bounds__(256)
void k_pool_bf(const unsigned short* __restrict__ x, const float* __restrict__ Wlin,
               const float* __restrict__ blin, float* __restrict__ out)
{
    int g = blockIdx.x;
    int tid = threadIdx.x;
    const unsigned short* base = x + (size_t)g * 128 * 512;
    float a0 = 0.f, a1 = 0.f;
    for (int r = 0; r < 128; ++r) {
        unsigned v = *(const unsigned*)(base + r * 512 + 2 * tid);
        a0 += bf2f((unsigned short)(v & 0xffff));
        a1 += bf2f((unsigned short)(v >> 16));
    }
    __shared__ float pooled[512];
    pooled[2*tid]     = a0 * (1.f / 128.f);
    pooled[2*tid + 1] = a1 * (1.f / 128.f);
    __syncthreads();
    if (tid < 64) {
        float p0 = 0.f, p1 = 0.f;
        for (int k = tid; k < 512; k += 64) {
            float pv = pooled[k];
            p0 += pv * Wlin[2*k];
            p1 += pv * Wlin[2*k + 1];
        }
        #pragma unroll
        for (int off = 32; off >= 1; off >>= 1) {
            p0 += __shfl_xor(p0, off);
            p1 += __shfl_xor(p1, off);
        }
        if (tid == 0) {
            out[2*g]     = p0 + blin[0];
            out[2*g + 1] = p1 + blin[1];
        }
    }
}

extern "C" void kernel_launch(void* const* d_in, const int* in_sizes, int n_in,
                              void* d_out, int out_size, void* d_ws, size_t ws_size,
                              hipStream_t stream)
{
    (void)in_sizes; (void)n_in; (void)out_size; (void)ws_size;
    const int*   word_seq = (const int*)  d_in[0];
    const int*   ei       = (const int*)  d_in[1];
    const float* tab      = (const float*)d_in[3];
    const float* wih_f    = (const float*)d_in[4];
    const float* whh_f    = (const float*)d_in[5];
    const float* b_f      = (const float*)d_in[6];
    const float* wih_b    = (const float*)d_in[7];
    const float* whh_b    = (const float*)d_in[8];
    const float* b_b      = (const float*)d_in[9];
    const float* Wl1      = (const float*)d_in[10];
    const float* Wr1      = (const float*)d_in[11];
    const float* b1       = (const float*)d_in[12];
    const float* Wl2      = (const float*)d_in[13];
    const float* Wr2      = (const float*)d_in[14];
    const float* b2       = (const float*)d_in[15];
    const float* Wl3      = (const float*)d_in[16];
    const float* Wr3      = (const float*)d_in[17];
    const float* b3       = (const float*)d_in[18];
    const float* Wlin     = (const float*)d_in[19];
    const float* blin     = (const float*)d_in[20];
    float* out = (float*)d_out;

    char* w = (char*)d_ws;
    int*   deg    = (int*)  (w);                     //     65,536
    int*   indptr = (int*)  (w + 65536);             //     66,048
    int*   fill   = (int*)  (w + 131584);            //     65,536
    int*   cols   = (int*)  (w + 197120);            //  1,048,576
    unsigned long long* hx = (unsigned long long*)(w + 1245696);   // 524,288
    unsigned short* whhp_f = (unsigned short*)(w + 1769984);       // 524,288
    unsigned short* whhp_b = (unsigned short*)(w + 2294272);       // 524,288
    float* pb_f   = (float*)(w + 2818560);           //      4,096
    float* pb_b   = (float*)(w + 2822656);           //      4,096
    unsigned short* wt_f = (unsigned short*)(w + 2826752);   // 655,360
    unsigned short* wt_b = (unsigned short*)(w + 3482112);   // 655,360
    unsigned short* wc1  = (unsigned short*)(w + 4137472);   // 1,048,576
    unsigned short* wc2  = (unsigned short*)(w + 5186048);   // 1,048,576
    unsigned short* wc3  = (unsigned short*)(w + 6234624);   // 1,048,576
    unsigned short* xeb  = (unsigned short*)(w + 7283200);   // 10,485,760
    float* xs_f   = (float*)(w + 17768960);          // 67,108,864
    float* xs_b   = (float*)(w + 84877824);          // 67,108,864
    unsigned short* x0b = (unsigned short*)(w + 151986688);  // 16,777,216 (end ~161 MB)
    // post-LSTM reuse of xs regions:
    unsigned short* catb = (unsigned short*)(w + 17768960);  // 32 MB in xs_f
    float* x1     = (float*)(w + 51323392);          // 32 MB in xs_f
    unsigned short* xb_a = (unsigned short*)(w + 84877824);  // 16 MB in xs_b
    unsigned short* xb_b = (unsigned short*)(w + 101655040); // 16 MB in xs_b

    // conversions + embedding (bf16, vectorized 16B/thread)
    k_embed_bf<<<2560, 256, 0, stream>>>(word_seq, tab, xeb);
    k_cvt_wih<<<160, 256, 0, stream>>>(wih_f, wt_f);
    k_cvt_wih<<<160, 256, 0, stream>>>(wih_b, wt_b);
    k_cvt_whh<<<128, 256, 0, stream>>>(whh_f, whhp_f);
    k_cvt_whh<<<128, 256, 0, stream>>>(whh_b, whhp_b);
    k_permb<<<4, 256, 0, stream>>>(b_f, pb_f);
    k_permb<<<4, 256, 0, stream>>>(b_b, pb_b);
    k_cvt_wcat<<<2048, 256, 0, stream>>>(Wl1, Wr1, wc1);
    k_cvt_wcat<<<2048, 256, 0, stream>>>(Wl2, Wr2, wc2);
    k_cvt_wcat<<<2048, 256, 0, stream>>>(Wl3, Wr3, wc3);

    // CSR build + hx tag clear
    k_init<<<256, 256, 0, stream>>>(hx, deg, fill);
    k_hist<<<1024, 256, 0, stream>>>(ei, deg);
    k_scan<<<1, 256, 0, stream>>>(deg, indptr);
    k_scatter<<<1024, 256, 0, stream>>>(ei, indptr, fill, cols);

    // LSTM input projections (bf16 MFMA): xs = xeb @ wt^T + pb (permuted cols)
    k_mgemm<<<dim3(128, 8), 256, 0, stream>>>(xeb, wt_f, pb_f, xs_f, 1024, 320);
    k_mgemm<<<dim3(128, 8), 256, 0, stream>>>(xeb, wt_b, pb_b, xs_b, 1024, 320);

    // bidirectional LSTM scan -> x0b = [hf | hb] (bf16)
    k_lstm<<<64, 512, 0, stream>>>(xs_f, xs_b, whhp_f, whhp_b, x0b, hx);

    // SAGE layer 1
    k_gather_lds<<<256, 512, 131072, stream>>>(x0b, indptr, cols, catb);
    k_mgemm<<<dim3(128, 4), 256, 0, stream>>>(catb, wc1, b1, x1, 512, 1024);
    k_norm_relu_bf<<<4096, 256, 0, stream>>>(x1, xb_a);
    // SAGE layer 2
    k_gather_lds<<<256, 512, 131072, stream>>>(xb_a, indptr, cols, catb);
    k_mgemm<<<dim3(128, 4), 256, 0, stream>>>(catb, wc2, b2, x1, 512, 1024);
    k_norm_relu_bf<<<4096, 256, 0, stream>>>(x1, xb_b);
    // SAGE layer 3
    k_gather_lds<<<256, 512, 131072, stream>>>(xb_b, indptr, cols, catb);
    k_mgemm<<<dim3(128, 4), 256, 0, stream>>>(catb, wc3, b3, x1, 512, 1024);
    k_norm_relu_bf<<<4096, 256, 0, stream>>>(x1, xb_a);

    // mean pool per graph + linear head
    k_pool_bf<<<128, 256, 0, stream>>>(xb_a, Wlin, blin, out);
}

// Round 17
// 633.619 us; speedup vs baseline: 1.2798x; 1.0100x over previous
//
#include <hip/hip_runtime.h>
#include <math.h>

#define NN   16384
#define EE   262144

typedef __attribute__((ext_vector_type(8))) short  short8v;   // 8 bf16 = 4 VGPR
typedef __attribute__((ext_vector_type(4))) float  f32x4;

__device__ inline unsigned short f2bf(float f) {
    union { float f; unsigned u; } v; v.f = f;
    unsigned r = v.u + 0x7fff + ((v.u >> 16) & 1);   // RNE
    return (unsigned short)(r >> 16);
}
__device__ inline float bf2f(unsigned short b) {
    unsigned u = ((unsigned)b) << 16;
    union { unsigned u; float f; } v; v.u = u; return v.f;
}
__device__ inline float sigm_f(float x) { return 1.f / (1.f + __expf(-x)); }
__device__ inline float tanh_f(float x) {
    x = fminf(15.f, fmaxf(-15.f, x));
    float e = __expf(2.f * x);
    return (e - 1.f) / (e + 1.f);
}
// quarter-split gate-col permutation:
// n'' = Q*256 + wv*32 + tile*16 + tc,  tile in {0,1}, tc in [0,16)
// gate g = tile*2 + (tc>>3), hidden j = Q*64 + wv*8 + (tc&7), orig = g*256 + j
__device__ inline int gate_orig2(int np) {
    int Q = np >> 8, wv = (np >> 5) & 7, tile = (np >> 4) & 1, tc = np & 15;
    int g = tile * 2 + (tc >> 3);
    int j = Q * 64 + wv * 8 + (tc & 7);
    return g * 256 + j;
}

// ---------------- init (zero hx tags / deg / fill) ----------------
__global__ void k_init(unsigned long long* __restrict__ hx, int* __restrict__ deg,
                       int* __restrict__ fill) {
    int i = blockIdx.x * 256 + threadIdx.x;
    if (i < 65536) hx[i] = 0ull;            // tag=0 matches no wanted tag (>=1)
    if (i < NN) { deg[i] = 0; fill[i] = 0; }
}

// ---------------- embedding gather -> bf16, K padded 300->320 (vectorized 16B/thr) ----------------
__global__ void k_embed_bf(const int* __restrict__ wseq, const float* __restrict__ tab,
                           unsigned short* __restrict__ xeb) {
    int i = blockIdx.x * 256 + threadIdx.x;          // chunk of 8 elems
    if (i >= NN * 40) return;
    int row = i / 40, c8 = i - row * 40;
    int k = c8 * 8;
    unsigned short o[8];
    const float* tp = tab + (size_t)wseq[row] * 300;  // row base: 1200 B (16B aligned)
    if (k + 8 <= 300) {
        float4 v0 = *(const float4*)(tp + k);
        float4 v1 = *(const float4*)(tp + k + 4);
        o[0]=f2bf(v0.x); o[1]=f2bf(v0.y); o[2]=f2bf(v0.z); o[3]=f2bf(v0.w);
        o[4]=f2bf(v1.x); o[5]=f2bf(v1.y); o[6]=f2bf(v1.z); o[7]=f2bf(v1.w);
    } else {
        #pragma unroll
        for (int q = 0; q < 8; ++q) {
            int kk = k + q;
            o[q] = f2bf(kk < 300 ? tp[kk] : 0.f);
        }
    }
    *(short8v*)(xeb + (size_t)row * 320 + k) = *(short8v*)o;
}

// ---------------- weight conversions (gate_orig2 permutation, vectorized) ----------------
__global__ void k_cvt_wih(const float* __restrict__ wih, unsigned short* __restrict__ wt) {
    int i = blockIdx.x * 256 + threadIdx.x;
    if (i >= 1024 * 40) return;
    int np = i / 40, c8 = i - np * 40;
    int k = c8 * 8;
    const float* src = wih + (size_t)gate_orig2(np) * 300;   // 1200 B rows, 16B aligned
    unsigned short o[8];
    if (k + 8 <= 300) {
        float4 v0 = *(const float4*)(src + k);
        float4 v1 = *(const float4*)(src + k + 4);
        o[0]=f2bf(v0.x); o[1]=f2bf(v0.y); o[2]=f2bf(v0.z); o[3]=f2bf(v0.w);
        o[4]=f2bf(v1.x); o[5]=f2bf(v1.y); o[6]=f2bf(v1.z); o[7]=f2bf(v1.w);
    } else {
        #pragma unroll
        for (int q = 0; q < 8; ++q) {
            int kk = k + q;
            o[q] = f2bf(kk < 300 ? src[kk] : 0.f);
        }
    }
    *(short8v*)(wt + (size_t)np * 320 + k) = *(short8v*)o;
}
__global__ void k_cvt_whh(const float* __restrict__ whh, unsigned short* __restrict__ wp) {
    int i = blockIdx.x * 256 + threadIdx.x;
    if (i >= 1024 * 32) return;
    int np = i >> 5, kc = i & 31;
    int k = kc * 8;
    const float* src = whh + (size_t)gate_orig2(np) * 256 + k;  // 1024 B rows
    float4 v0 = *(const float4*)src;
    float4 v1 = *(const float4*)(src + 4);
    unsigned short o[8];
    o[0]=f2bf(v0.x); o[1]=f2bf(v0.y); o[2]=f2bf(v0.z); o[3]=f2bf(v0.w);
    o[4]=f2bf(v1.x); o[5]=f2bf(v1.y); o[6]=f2bf(v1.z); o[7]=f2bf(v1.w);
    *(short8v*)(wp + (size_t)np * 256 + k) = *(short8v*)o;
}
__global__ void k_permb(const float* __restrict__ b, float* __restrict__ pb) {
    int i = blockIdx.x * 256 + threadIdx.x;
    if (i < 1024) pb[i] = b[gate_orig2(i)];
}
__global__ void k_cvt_wcat(const float* __restrict__ Wl, const float* __restrict__ Wr,
                           unsigned short* __restrict__ wc) {
    int i = blockIdx.x * 256 + threadIdx.x;
    if (i >= 512 * 1024) return;
    int n = i >> 10, k = i & 1023;
    float f = (k < 512) ? Wl[k * 512 + n] : Wr[(k - 512) * 512 + n];
    wc[i] = f2bf(f);
}

// ---------------- bf16 MFMA GEMM: C[M][N] = A[M][Ka] * Bt[N][Ka]^T + bias, bf16 out ----------------
__global__ __launch_bounds__(256)
void k_mgemm(const unsigned short* __restrict__ A, const unsigned short* __restrict__ Bt,
             const float* __restrict__ bias, unsigned short* __restrict__ C, int N, int Ka)
{
    __shared__ unsigned short As[128 * 32];
    __shared__ unsigned short Bs[128 * 32];
    const int tid = threadIdx.x;
    const int m0 = blockIdx.x << 7, n0 = blockIdx.y << 7;
    const int w = tid >> 6, lane = tid & 63;
    const int wr = w >> 1, wc = w & 1;
    const int lr = lane & 15, lhi = lane >> 4;
    const int r0 = tid >> 2, kc0 = (tid & 3) * 8;

    f32x4 acc[4][4] = {};

    for (int k0 = 0; k0 < Ka; k0 += 32) {
        short8v a0 = *(const short8v*)(A + (m0 + r0) * Ka + k0 + kc0);
        short8v a1 = *(const short8v*)(A + (m0 + 64 + r0) * Ka + k0 + kc0);
        short8v b0 = *(const short8v*)(Bt + (n0 + r0) * Ka + k0 + kc0);
        short8v b1 = *(const short8v*)(Bt + (n0 + 64 + r0) * Ka + k0 + kc0);
        __syncthreads();
        *(short8v*)&As[r0 * 32 + kc0]        = a0;
        *(short8v*)&As[(64 + r0) * 32 + kc0] = a1;
        *(short8v*)&Bs[r0 * 32 + kc0]        = b0;
        *(short8v*)&Bs[(64 + r0) * 32 + kc0] = b1;
        __syncthreads();
        short8v af[4], bf[4];
        #pragma unroll
        for (int i = 0; i < 4; ++i)
            af[i] = *(const short8v*)&As[(wr * 64 + i * 16 + lr) * 32 + lhi * 8];
        #pragma unroll
        for (int j = 0; j < 4; ++j)
            bf[j] = *(const short8v*)&Bs[(wc * 64 + j * 16 + lr) * 32 + lhi * 8];
        #pragma unroll
        for (int i = 0; i < 4; ++i)
            #pragma unroll
            for (int j = 0; j < 4; ++j)
                acc[i][j] = __builtin_amdgcn_mfma_f32_16x16x32_bf16(af[i], bf[j], acc[i][j], 0, 0, 0);
    }
    #pragma unroll
    for (int i = 0; i < 4; ++i) {
        int row = m0 + wr * 64 + i * 16 + lhi * 4;
        #pragma unroll
        for (int j = 0; j < 4; ++j) {
            int col = n0 + wc * 64 + j * 16 + lr;
            float bv = bias[col];
            #pragma unroll
            for (int r = 0; r < 4; ++r)
                C[(size_t)(row + r) * N + col] = f2bf(acc[i][j][r] + bv);
        }
    }
}

// ---------------- LSTM recurrence: quarter-split, occupancy pinned, bf16 xs ----------------
__global__ __attribute__((amdgpu_waves_per_eu(2, 2))) __launch_bounds__(512)
void k_lstm(const unsigned short* __restrict__ xs_f, const unsigned short* __restrict__ xs_b,
            const unsigned short* __restrict__ whhp_f, const unsigned short* __restrict__ whhp_b,
            unsigned short* __restrict__ xout, unsigned long long* __restrict__ hx)
{
    const int tid  = threadIdx.x;
    const int wv   = tid >> 6, lane = tid & 63;
    const int lr16 = lane & 15, lh = lane >> 4;
    const int b3   = (lane >> 3) & 1, lr3 = lane & 7;
    const int wgid = blockIdx.x;            // dir*32 + bs*4 + Q
    const int dir  = wgid >> 5;
    const int bs   = (wgid >> 2) & 7;
    const int Q    = wgid & 3;
    const int b0   = bs * 16;
    const unsigned short* xs = dir ? xs_b : xs_f;
    const unsigned short* whhp = dir ? whhp_b : whhp_f;

    // B-frag preload: 2 tiles x 8 ks = 64 VGPRs
    const int ncol0 = Q * 256 + wv * 32 + lr16;     // tile0 col; tile1 = +16
    short8v wf[2][8];
    #pragma unroll
    for (int tt = 0; tt < 2; ++tt)
        #pragma unroll
        for (int ks = 0; ks < 8; ++ks)
            wf[tt][ks] = *(const short8v*)(whhp
                + (size_t)(ncol0 + tt * 16) * 256 + ks * 32 + lh * 8);

    __shared__ unsigned short At[2][16 * 256];      // [parity][row][j] bf16, swizzled

    const int grpbase = (dir * 8 + bs) * 4 * 1024;  // 4 quarter-wgs x 1024 words
    unsigned long long* hx_own = hx + grpbase + Q * 1024;

    const int jmine = Q * 64 + wv * 8 + lr3;        // my hidden index
    const int rowb  = 4 * lh;
    const int myr0  = rowb + 2 * b3;                // my 2 rows: myr0, myr0+1
    // unpack role: word w = tid of each peer -> (j_local, row pair)
    const int up_jl = (tid >> 6) * 8 + (tid & 7);
    const int up_r0 = 2 * ((tid >> 3) & 7);

    float c0 = 0.f, c1 = 0.f;
    float xv0[4], xv1[4];                           // x at my 2 cols, 4 rows
    {
        const int l0 = dir ? 127 : 0;
        #pragma unroll
        for (int r = 0; r < 4; ++r) {
            const unsigned short* xp = xs + ((size_t)(b0 + rowb + r) * 128 + l0) * 1024;
            xv0[r] = bf2f(xp[ncol0]);
            xv1[r] = bf2f(xp[ncol0 + 16]);
        }
    }

    for (int t = 0; t < 128; ++t) {
        const int l = dir ? (127 - t) : t;
        f32x4 acc0 = {}, acc1 = {};
        if (t > 0) {
            const char* Ab = (const char*)&At[(t - 1) & 1][0];
            #pragma unroll
            for (int ks = 0; ks < 8; ++ks) {
                int off = (lr16 * 512 + ks * 64 + lh * 16) ^ ((lr16 & 7) << 4);
                short8v a = *(const short8v*)(Ab + off);
                acc0 = __builtin_amdgcn_mfma_f32_16x16x32_bf16(a, wf[0][ks], acc0, 0, 0, 0);
                acc1 = __builtin_amdgcn_mfma_f32_16x16x32_bf16(a, wf[1][ks], acc1, 0, 0, 0);
            }
        }
        #pragma unroll
        for (int r = 0; r < 4; ++r) { acc0[r] += xv0[r]; acc1[r] += xv1[r]; }
        // swap row-halves with partner lane^8 (partner holds the other gate pair)
        float z0 = b3 ? acc0[0] : acc0[2];
        float z1 = b3 ? acc0[1] : acc0[3];
        float z2 = b3 ? acc1[0] : acc1[2];
        float z3 = b3 ? acc1[1] : acc1[3];
        float y0 = __shfl_xor(z0, 8);
        float y1 = __shfl_xor(z1, 8);
        float y2 = __shfl_xor(z2, 8);
        float y3 = __shfl_xor(z3, 8);
        float iv0 = b3 ? y0 : acc0[0], iv1 = b3 ? y1 : acc0[1];
        float fv0 = b3 ? acc0[2] : y0, fv1 = b3 ? acc0[3] : y1;
        float gv0 = b3 ? y2 : acc1[0], gv1 = b3 ? y3 : acc1[1];
        float ov0 = b3 ? acc1[2] : y2, ov1 = b3 ? acc1[3] : y3;
        // gates for my 2 rows
        iv0 = sigm_f(iv0); fv0 = sigm_f(fv0); gv0 = tanh_f(gv0); ov0 = sigm_f(ov0);
        c0 = fv0 * c0 + iv0 * gv0;
        float h0 = ov0 * tanh_f(c0);
        iv1 = sigm_f(iv1); fv1 = sigm_f(fv1); gv1 = tanh_f(gv1); ov1 = sigm_f(ov1);
        c1 = fv1 * c1 + iv1 * gv1;
        float h1 = ov1 * tanh_f(c1);
        unsigned short hb0 = f2bf(h0), hb1 = f2bf(h1);
        xout[((size_t)(b0 + myr0)     * 128 + l) * 512 + dir * 256 + jmine] = hb0;
        xout[((size_t)(b0 + myr0 + 1) * 128 + l) * 512 + dir * 256 + jmine] = hb1;

        if (t < 127) {
            const int p = t & 1;
            char* Aw = (char*)&At[p][0];
            {
                int r0_ = myr0, r1_ = myr0 + 1;
                *(unsigned short*)(Aw + ((r0_ * 512 + 2 * jmine) ^ ((r0_ & 7) << 4))) = hb0;
                *(unsigned short*)(Aw + ((r1_ * 512 + 2 * jmine) ^ ((r1_ & 7) << 4))) = hb1;
            }
            const unsigned tg = (unsigned)(t + 1);
            unsigned long long w = ((unsigned long long)tg << 32)
                                 | ((unsigned)hb0 | ((unsigned)hb1 << 16));
            __hip_atomic_store(hx_own + p * 512 + tid, w,
                               __ATOMIC_RELAXED, __HIP_MEMORY_SCOPE_AGENT);
            // prefetch xs(t+1)
            const int l2 = dir ? (126 - t) : (t + 1);
            #pragma unroll
            for (int r = 0; r < 4; ++r) {
                const unsigned short* xp = xs + ((size_t)(b0 + rowb + r) * 128 + l2) * 1024;
                xv0[r] = bf2f(xp[ncol0]);
                xv1[r] = bf2f(xp[ncol0 + 16]);
            }
            // poll 3 peer quarters (word w = tid each), unpack into At
            const unsigned long long* pp1 = hx + grpbase + (Q ^ 1) * 1024 + p * 512 + tid;
            const unsigned long long* pp2 = hx + grpbase + (Q ^ 2) * 1024 + p * 512 + tid;
            const unsigned long long* pp3 = hx + grpbase + (Q ^ 3) * 1024 + p * 512 + tid;
            unsigned long long u1 = __hip_atomic_load(pp1, __ATOMIC_RELAXED, __HIP_MEMORY_SCOPE_AGENT);
            unsigned long long u2 = __hip_atomic_load(pp2, __ATOMIC_RELAXED, __HIP_MEMORY_SCOPE_AGENT);
            unsigned long long u3 = __hip_atomic_load(pp3, __ATOMIC_RELAXED, __HIP_MEMORY_SCOPE_AGENT);
            while ((unsigned)(u1 >> 32) != tg)
                u1 = __hip_atomic_load(pp1, __ATOMIC_RELAXED, __HIP_MEMORY_SCOPE_AGENT);
            while ((unsigned)(u2 >> 32) != tg)
                u2 = __hip_atomic_load(pp2, __ATOMIC_RELAXED, __HIP_MEMORY_SCOPE_AGENT);
            while ((unsigned)(u3 >> 32) != tg)
                u3 = __hip_atomic_load(pp3, __ATOMIC_RELAXED, __HIP_MEMORY_SCOPE_AGENT);
            {
                int ra = up_r0, rb = up_r0 + 1;
                int j1 = (Q ^ 1) * 64 + up_jl;
                int j2 = (Q ^ 2) * 64 + up_jl;
                int j3 = (Q ^ 3) * 64 + up_jl;
                *(unsigned short*)(Aw + ((ra * 512 + 2 * j1) ^ ((ra & 7) << 4))) =
                    (unsigned short)(u1 & 0xffff);
                *(unsigned short*)(Aw + ((rb * 512 + 2 * j1) ^ ((rb & 7) << 4))) =
                    (unsigned short)((u1 >> 16) & 0xffff);
                *(unsigned short*)(Aw + ((ra * 512 + 2 * j2) ^ ((ra & 7) << 4))) =
                    (unsigned short)(u2 & 0xffff);
                *(unsigned short*)(Aw + ((rb * 512 + 2 * j2) ^ ((rb & 7) << 4))) =
                    (unsigned short)((u2 >> 16) & 0xffff);
                *(unsigned short*)(Aw + ((ra * 512 + 2 * j3) ^ ((ra & 7) << 4))) =
                    (unsigned short)(u3 & 0xffff);
                *(unsigned short*)(Aw + ((rb * 512 + 2 * j3) ^ ((rb & 7) << 4))) =
                    (unsigned short)((u3 >> 16) & 0xffff);
            }
            __syncthreads();
        }
    }
}

// ---------------- CSR build ----------------
__global__ void k_hist(const int* __restrict__ ei, int* __restrict__ deg) {
    int e = blockIdx.x * 256 + threadIdx.x;
    if (e >= EE) return;
    atomicAdd(&deg[ei[EE + e]], 1);
}

__global__ void k_scan(const int* __restrict__ deg, int* __restrict__ indptr) {
    __shared__ int sm[256];
    int tid = threadIdx.x;
    int b0 = tid * 64;
    int s = 0;
    for (int i = 0; i < 64; ++i) s += deg[b0 + i];
    sm[tid] = s;
    __syncthreads();
    for (int off = 1; off < 256; off <<= 1) {
        int v = (tid >= off) ? sm[tid - off] : 0;
        __syncthreads();
        sm[tid] += v;
        __syncthreads();
    }
    int run = sm[tid] - s;   // exclusive prefix
    for (int i = 0; i < 64; ++i) { indptr[b0 + i] = run; run += deg[b0 + i]; }
    if (tid == 255) indptr[NN] = run;
}

__global__ void k_scatter(const int* __restrict__ ei, const int* __restrict__ indptr,
                          int* __restrict__ fill, int* __restrict__ cols) {
    int e = blockIdx.x * 256 + threadIdx.x;
    if (e >= EE) return;
    int d = ei[EE + e];
    int slot = atomicAdd(&fill[d], 1);
    cols[indptr[d] + slot] = ei[e];
}

// ---------------- SAGE gather, graph-local via LDS ----------------
__global__ __launch_bounds__(512)
void k_gather_lds(const unsigned short* __restrict__ x, const int* __restrict__ indptr,
                  const int* __restrict__ cols, unsigned short* __restrict__ catb)
{
    extern __shared__ char gsm[];
    unsigned short* Xs = (unsigned short*)gsm;     // [128][512] bf16 = 128 KB
    const int tid  = threadIdx.x;
    const int g    = blockIdx.x >> 1;
    const int hf   = blockIdx.x & 1;
    const int base = g * 128;
    {   // stage: 131072 B = 512 thr x 16 B x 16 iters, fully coalesced
        const unsigned short* src = x + (size_t)base * 512;
        #pragma unroll
        for (int it = 0; it < 16; ++it) {
            int i = it * 512 + tid;                // 16B-chunk index; 64 chunks/row
            int row = i >> 6, c = (i & 63) * 8;
            *(short8v*)(Xs + row * 512 + c) = *(const short8v*)(src + (size_t)row * 512 + c);
        }
    }
    __syncthreads();
    const int wv = tid >> 6, lane = tid & 63;
    for (int rr = 0; rr < 8; ++rr) {
        int node = base + hf * 64 + rr * 8 + wv;
        int s = indptr[node], e = indptr[node + 1];
        float a[8] = {};
        for (int p = s; p < e; ++p) {
            int lrow = cols[p] - base;             // local row in [0,128)
            short8v v = *(const short8v*)(Xs + lrow * 512 + lane * 8);
            #pragma unroll
            for (int q = 0; q < 8; ++q) a[q] += bf2f((unsigned short)v[q]);
        }
        float sc = 1.f / (float)((e - s) > 1 ? (e - s) : 1);
        unsigned short o[8];
        #pragma unroll
        for (int q = 0; q < 8; ++q) o[q] = f2bf(a[q] * sc);
        unsigned short* cp = catb + (size_t)node * 1024 + lane * 8;
        *(short8v*)cp = *(short8v*)o;
        *(short8v*)(cp + 512) = *(const short8v*)(Xs + (node - base) * 512 + lane * 8);
    }
}

// ---------------- row L2-normalize + relu: bf16 in -> bf16 out ----------------
__global__ __launch_bounds__(256)
void k_norm_relu_bb(const unsigned short* __restrict__ y, unsigned short* __restrict__ o)
{
    int gw = (blockIdx.x * 256 + threadIdx.x) >> 6;
    int lane = threadIdx.x & 63;
    if (gw >= NN) return;
    short8v v = *(const short8v*)(y + (size_t)gw * 512 + lane * 8);
    float f[8];
    #pragma unroll
    for (int q = 0; q < 8; ++q) f[q] = bf2f((unsigned short)v[q]);
    float ss = 0.f;
    #pragma unroll
    for (int q = 0; q < 8; ++q) ss += f[q] * f[q];
    #pragma unroll
    for (int off = 32; off >= 1; off >>= 1) ss += __shfl_xor(ss, off);
    float sc = 1.f / fmaxf(sqrtf(ss), 1e-12f);
    unsigned short ob[8];
    #pragma unroll
    for (int q = 0; q < 8; ++q) ob[q] = f2bf(fmaxf(f[q] * sc, 0.f));
    *(short8v*)(o + (size_t)gw * 512 + lane * 8) = *(short8v*)ob;
}

// ---------------- mean-pool per graph + linear head (bf16 in) ----------------
__global__ __launch_bounds__(256)
void k_pool_bf(const unsigned short* __restrict__ x, const float* __restrict__ Wlin,
               const float* __restrict__ blin, float* __restrict__ out)
{
    int g = blockIdx.x;
    int tid = threadIdx.x;
    const unsigned short* base = x + (size_t)g * 128 * 512;
    float a0 = 0.f, a1 = 0.f;
    for (int r = 0; r < 128; ++r) {
        unsigned v = *(const unsigned*)(base + r * 512 + 2 * tid);
        a0 += bf2f((unsigned short)(v & 0xffff));
        a1 += bf2f((unsigned short)(v >> 16));
    }
    __shared__ float pooled[512];
    pooled[2*tid]     = a0 * (1.f / 128.f);
    pooled[2*tid + 1] = a1 * (1.f / 128.f);
    __syncthreads();
    if (tid < 64) {
        float p0 = 0.f, p1 = 0.f;
        for (int k = tid; k < 512; k += 64) {
            float pv = pooled[k];
            p0 += pv * Wlin[2*k];
            p1 += pv * Wlin[2*k + 1];
        }
        #pragma unroll
        for (int off = 32; off >= 1; off >>= 1) {
            p0 += __shfl_xor(p0, off);
            p1 += __shfl_xor(p1, off);
        }
        if (tid == 0) {
            out[2*g]     = p0 + blin[0];
            out[2*g + 1] = p1 + blin[1];
        }
    }
}

extern "C" void kernel_launch(void* const* d_in, const int* in_sizes, int n_in,
                              void* d_out, int out_size, void* d_ws, size_t ws_size,
                              hipStream_t stream)
{
    (void)in_sizes; (void)n_in; (void)out_size; (void)ws_size;
    const int*   word_seq = (const int*)  d_in[0];
    const int*   ei       = (const int*)  d_in[1];
    const float* tab      = (const float*)d_in[3];
    const float* wih_f    = (const float*)d_in[4];
    const float* whh_f    = (const float*)d_in[5];
    const float* b_f      = (const float*)d_in[6];
    const float* wih_b    = (const float*)d_in[7];
    const float* whh_b    = (const float*)d_in[8];
    const float* b_b      = (const float*)d_in[9];
    const float* Wl1      = (const float*)d_in[10];
    const float* Wr1      = (const float*)d_in[11];
    const float* b1       = (const float*)d_in[12];
    const float* Wl2      = (const float*)d_in[13];
    const float* Wr2      = (const float*)d_in[14];
    const float* b2       = (const float*)d_in[15];
    const float* Wl3      = (const float*)d_in[16];
    const float* Wr3      = (const float*)d_in[17];
    const float* b3       = (const float*)d_in[18];
    const float* Wlin     = (const float*)d_in[19];
    const float* blin     = (const float*)d_in[20];
    float* out = (float*)d_out;

    char* w = (char*)d_ws;
    int*   deg    = (int*)  (w);                     //     65,536
    int*   indptr = (int*)  (w + 65536);             //     66,048
    int*   fill   = (int*)  (w + 131584);            //     65,536
    int*   cols   = (int*)  (w + 197120);            //  1,048,576
    unsigned long long* hx = (unsigned long long*)(w + 1245696);   // 524,288
    unsigned short* whhp_f = (unsigned short*)(w + 1769984);       // 524,288
    unsigned short* whhp_b = (unsigned short*)(w + 2294272);       // 524,288
    float* pb_f   = (float*)(w + 2818560);           //      4,096
    float* pb_b   = (float*)(w + 2822656);           //      4,096
    unsigned short* wt_f = (unsigned short*)(w + 2826752);   // 655,360
    unsigned short* wt_b = (unsigned short*)(w + 3482112);   // 655,360
    unsigned short* wc1  = (unsigned short*)(w + 4137472);   // 1,048,576
    unsigned short* wc2  = (unsigned short*)(w + 5186048);   // 1,048,576
    unsigned short* wc3  = (unsigned short*)(w + 6234624);   // 1,048,576
    unsigned short* xeb  = (unsigned short*)(w + 7283200);   // 10,485,760
    unsigned short* xs_f = (unsigned short*)(w + 17768960);  // 33,554,432 (bf16)
    unsigned short* xs_b = (unsigned short*)(w + 51323392);  // 33,554,432 (bf16)
    unsigned short* x0b  = (unsigned short*)(w + 84877824);  // 16,777,216
    // post-LSTM reuse:
    unsigned short* catb = (unsigned short*)(w + 17768960);  // 32 MB (old xs_f)
    unsigned short* y1   = (unsigned short*)(w + 51323392);  // 16 MB (old xs_b lo)
    unsigned short* xb_a = (unsigned short*)(w + 68100608);  // 16 MB (old xs_b hi)
    unsigned short* xb_b = (unsigned short*)(w + 101655040); // 16 MB (after x0b)

    // conversions + embedding (bf16, vectorized 16B/thread)
    k_embed_bf<<<2560, 256, 0, stream>>>(word_seq, tab, xeb);
    k_cvt_wih<<<160, 256, 0, stream>>>(wih_f, wt_f);
    k_cvt_wih<<<160, 256, 0, stream>>>(wih_b, wt_b);
    k_cvt_whh<<<128, 256, 0, stream>>>(whh_f, whhp_f);
    k_cvt_whh<<<128, 256, 0, stream>>>(whh_b, whhp_b);
    k_permb<<<4, 256, 0, stream>>>(b_f, pb_f);
    k_permb<<<4, 256, 0, stream>>>(b_b, pb_b);
    k_cvt_wcat<<<2048, 256, 0, stream>>>(Wl1, Wr1, wc1);
    k_cvt_wcat<<<2048, 256, 0, stream>>>(Wl2, Wr2, wc2);
    k_cvt_wcat<<<2048, 256, 0, stream>>>(Wl3, Wr3, wc3);

    // CSR build + hx tag clear
    k_init<<<256, 256, 0, stream>>>(hx, deg, fill);
    k_hist<<<1024, 256, 0, stream>>>(ei, deg);
    k_scan<<<1, 256, 0, stream>>>(deg, indptr);
    k_scatter<<<1024, 256, 0, stream>>>(ei, indptr, fill, cols);

    // LSTM input projections (bf16 MFMA, bf16 out): xs = xeb @ wt^T + pb
    k_mgemm<<<dim3(128, 8), 256, 0, stream>>>(xeb, wt_f, pb_f, xs_f, 1024, 320);
    k_mgemm<<<dim3(128, 8), 256, 0, stream>>>(xeb, wt_b, pb_b, xs_b, 1024, 320);

    // bidirectional LSTM scan -> x0b = [hf | hb] (bf16)
    k_lstm<<<64, 512, 0, stream>>>(xs_f, xs_b, whhp_f, whhp_b, x0b, hx);

    // SAGE layer 1
    k_gather_lds<<<256, 512, 131072, stream>>>(x0b, indptr, cols, catb);
    k_mgemm<<<dim3(128, 4), 256, 0, stream>>>(catb, wc1, b1, y1, 512, 1024);
    k_norm_relu_bb<<<4096, 256, 0, stream>>>(y1, xb_a);
    // SAGE layer 2
    k_gather_lds<<<256, 512, 131072, stream>>>(xb_a, indptr, cols, catb);
    k_mgemm<<<dim3(128, 4), 256, 0, stream>>>(catb, wc2, b2, y1, 512, 1024);
    k_norm_relu_bb<<<4096, 256, 0, stream>>>(y1, xb_b);
    // SAGE layer 3
    k_gather_lds<<<256, 512, 131072, stream>>>(xb_b, indptr, cols, catb);
    k_mgemm<<<dim3(128, 4), 256, 0, stream>>>(catb, wc3, b3, y1, 512, 1024);
    k_norm_relu_bb<<<4096, 256, 0, stream>>>(y1, xb_a);

    // mean pool per graph + linear head
    k_pool_bf<<<128, 256, 0, stream>>>(xb_a, Wlin, blin, out);
}